// Round 1
// baseline (757.256 us; speedup 1.0000x reference)
//
#include <hip/hip_runtime.h>
#include <hip/hip_bf16.h>

// Round 1: correctness-first all-fp32 implementation.
// - proj_kernel: C = A @ W + bias, output stored head-transposed [B, H, S, 64]
//   64x64 tile, BK=32, 256 threads, 4x4 register micro-tile per thread.
// - attn_kernel: flash-style fused attention per (b, h, 64-row q-tile),
//   64-key tiles, online softmax, fp32 accumulation throughout.
// Workspace layout: qh (8MB) | kh (16MB) | vh (16MB) = 40MB of d_ws.

__global__ __launch_bounds__(256) void proj_kernel(
    const float* __restrict__ A,    // [B*S, 512] row-major
    const float* __restrict__ Wm,   // [512, 512] row-major (in-dim major)
    const float* __restrict__ bias, // [512]
    float* __restrict__ dst,        // [B, 8, S, 64]
    int S)                          // rows per batch
{
    __shared__ float As[32][68];    // [k][row]  (+pad, 16B-aligned rows)
    __shared__ float Bs[32][68];    // [k][col]

    const int tid = threadIdx.x;
    const int m0 = blockIdx.y * 64;
    const int n0 = blockIdx.x * 64;
    const int g  = tid >> 4;        // 0..15 row group
    const int cg = tid & 15;        // 0..15 col group
    const int r0 = g * 4, c0 = cg * 4;

    const int arow = tid >> 3;          // 0..31
    const int akc  = (tid & 7) << 2;    // 0..28
    const int bkk  = tid >> 4;          // 0..15
    const int bc4  = (tid & 15) << 2;   // 0..60

    float acc[4][4];
    #pragma unroll
    for (int i = 0; i < 4; ++i)
        #pragma unroll
        for (int j = 0; j < 4; ++j) acc[i][j] = 0.f;

    for (int k0 = 0; k0 < 512; k0 += 32) {
        __syncthreads();   // protect LDS from previous iteration's readers
        #pragma unroll
        for (int pass = 0; pass < 2; ++pass) {
            int rr = arow + pass * 32;
            float4 v = *reinterpret_cast<const float4*>(
                &A[(size_t)(m0 + rr) * 512 + k0 + akc]);
            As[akc + 0][rr] = v.x;
            As[akc + 1][rr] = v.y;
            As[akc + 2][rr] = v.z;
            As[akc + 3][rr] = v.w;
            int kr = bkk + pass * 16;
            *reinterpret_cast<float4*>(&Bs[kr][bc4]) =
                *reinterpret_cast<const float4*>(
                    &Wm[(size_t)(k0 + kr) * 512 + n0 + bc4]);
        }
        __syncthreads();
        #pragma unroll
        for (int kk = 0; kk < 32; ++kk) {
            float4 a4 = *reinterpret_cast<const float4*>(&As[kk][r0]);
            float4 b4 = *reinterpret_cast<const float4*>(&Bs[kk][c0]);
            float a[4] = {a4.x, a4.y, a4.z, a4.w};
            float b[4] = {b4.x, b4.y, b4.z, b4.w};
            #pragma unroll
            for (int i = 0; i < 4; ++i)
                #pragma unroll
                for (int j = 0; j < 4; ++j)
                    acc[i][j] = fmaf(a[i], b[j], acc[i][j]);
        }
    }

    const int hh = n0 >> 6;    // head index (n0 is a multiple of 64)
    float4 bb4 = *reinterpret_cast<const float4*>(&bias[n0 + c0]);
    #pragma unroll
    for (int i = 0; i < 4; ++i) {
        int m = m0 + r0 + i;
        int b = m / S;
        int s = m - b * S;
        float4 o;
        o.x = acc[i][0] + bb4.x;
        o.y = acc[i][1] + bb4.y;
        o.z = acc[i][2] + bb4.z;
        o.w = acc[i][3] + bb4.w;
        *reinterpret_cast<float4*>(
            &dst[((((size_t)b * 8 + hh) * S + s) << 6) + c0]) = o;
    }
}

__global__ __launch_bounds__(256) void attn_kernel(
    const float* __restrict__ qh,   // [B, 8, 2048, 64]
    const float* __restrict__ kh,   // [B, 8, 4096, 64]
    const float* __restrict__ vh,   // [B, 8, 4096, 64]
    const int*   __restrict__ mask, // [B, 4096]
    float* __restrict__ out)        // [B, 2048, 512]
{
    __shared__ float Qs[64][68];    // [w][row]
    __shared__ float Ks[64][68];    // [w][key]
    __shared__ float Vs[64][68];    // [key][w]
    __shared__ float Ps[64][68];    // [row][key]
    __shared__ float msk[64];

    const int tid = threadIdx.x;
    const int qt = blockIdx.x;      // q tile, 0..31
    const int h  = blockIdx.y;      // head
    const int b  = blockIdx.z;      // batch
    const int bh = b * 8 + h;

    const float* Qg = qh + ((size_t)bh * 2048 + qt * 64) * 64;
    const float* Kg = kh + (size_t)bh * 4096 * 64;
    const float* Vg = vh + (size_t)bh * 4096 * 64;

    const int g  = tid >> 4;
    const int cg = tid & 15;
    const int r0 = g * 4, c0 = cg * 4;

    const int srow = tid >> 4;          // 0..15 staging row base
    const int sw4  = (tid & 15) << 2;   // 0..60

    // stage Q transposed: Qs[w][row]
    #pragma unroll
    for (int p = 0; p < 4; ++p) {
        int row = srow + p * 16;
        float4 v = *reinterpret_cast<const float4*>(&Qg[row * 64 + sw4]);
        Qs[sw4 + 0][row] = v.x;
        Qs[sw4 + 1][row] = v.y;
        Qs[sw4 + 2][row] = v.z;
        Qs[sw4 + 3][row] = v.w;
    }

    float m_run[4], l_run[4], O[4][4];
    #pragma unroll
    for (int i = 0; i < 4; ++i) {
        m_run[i] = -1e30f;
        l_run[i] = 0.f;
        #pragma unroll
        for (int j = 0; j < 4; ++j) O[i][j] = 0.f;
    }

    for (int kt = 0; kt < 4096; kt += 64) {
        __syncthreads();   // previous tile's readers of Ks/Vs/Ps are done
        #pragma unroll
        for (int p = 0; p < 4; ++p) {
            int key = srow + p * 16;
            float4 kv = *reinterpret_cast<const float4*>(
                &Kg[(size_t)(kt + key) * 64 + sw4]);
            Ks[sw4 + 0][key] = kv.x;
            Ks[sw4 + 1][key] = kv.y;
            Ks[sw4 + 2][key] = kv.z;
            Ks[sw4 + 3][key] = kv.w;
            float4 vv = *reinterpret_cast<const float4*>(
                &Vg[(size_t)(kt + key) * 64 + sw4]);
            *reinterpret_cast<float4*>(&Vs[key][sw4]) = vv;
        }
        if (tid < 64)
            msk[tid] = -10000.f * (1.f - (float)mask[b * 4096 + kt + tid]);
        __syncthreads();

        // S = Q K^T * 0.125 + mask_bias
        float s[4][4];
        #pragma unroll
        for (int i = 0; i < 4; ++i)
            #pragma unroll
            for (int j = 0; j < 4; ++j) s[i][j] = 0.f;
        #pragma unroll 16
        for (int w = 0; w < 64; ++w) {
            float4 a4 = *reinterpret_cast<const float4*>(&Qs[w][r0]);
            float4 b4 = *reinterpret_cast<const float4*>(&Ks[w][c0]);
            float a[4]  = {a4.x, a4.y, a4.z, a4.w};
            float bb[4] = {b4.x, b4.y, b4.z, b4.w};
            #pragma unroll
            for (int i = 0; i < 4; ++i)
                #pragma unroll
                for (int j = 0; j < 4; ++j)
                    s[i][j] = fmaf(a[i], bb[j], s[i][j]);
        }
        #pragma unroll
        for (int i = 0; i < 4; ++i)
            #pragma unroll
            for (int j = 0; j < 4; ++j)
                s[i][j] = fmaf(s[i][j], 0.125f, msk[c0 + j]);

        // online softmax (per row; 16 lanes of a row-group reduce together)
        #pragma unroll
        for (int i = 0; i < 4; ++i) {
            float t = fmaxf(fmaxf(s[i][0], s[i][1]), fmaxf(s[i][2], s[i][3]));
            t = fmaxf(t, __shfl_xor(t, 1, 16));
            t = fmaxf(t, __shfl_xor(t, 2, 16));
            t = fmaxf(t, __shfl_xor(t, 4, 16));
            t = fmaxf(t, __shfl_xor(t, 8, 16));
            float mnew = fmaxf(m_run[i], t);
            float sc = __expf(m_run[i] - mnew);
            float p0 = __expf(s[i][0] - mnew);
            float p1 = __expf(s[i][1] - mnew);
            float p2 = __expf(s[i][2] - mnew);
            float p3 = __expf(s[i][3] - mnew);
            float rs = (p0 + p1) + (p2 + p3);
            rs += __shfl_xor(rs, 1, 16);
            rs += __shfl_xor(rs, 2, 16);
            rs += __shfl_xor(rs, 4, 16);
            rs += __shfl_xor(rs, 8, 16);
            l_run[i] = l_run[i] * sc + rs;
            m_run[i] = mnew;
            #pragma unroll
            for (int j = 0; j < 4; ++j) O[i][j] *= sc;
            float4 p4; p4.x = p0; p4.y = p1; p4.z = p2; p4.w = p3;
            *reinterpret_cast<float4*>(&Ps[r0 + i][c0]) = p4;
        }
        __syncthreads();

        // O += P @ V   (output cols w0 = c0)
        #pragma unroll 16
        for (int c = 0; c < 64; ++c) {
            float4 v4 = *reinterpret_cast<const float4*>(&Vs[c][c0]);
            float vv[4] = {v4.x, v4.y, v4.z, v4.w};
            float a[4] = {Ps[r0 + 0][c], Ps[r0 + 1][c],
                          Ps[r0 + 2][c], Ps[r0 + 3][c]};
            #pragma unroll
            for (int i = 0; i < 4; ++i)
                #pragma unroll
                for (int j = 0; j < 4; ++j)
                    O[i][j] = fmaf(a[i], vv[j], O[i][j]);
        }
    }

    #pragma unroll
    for (int i = 0; i < 4; ++i) {
        float inv = 1.f / l_run[i];
        float4 o;
        o.x = O[i][0] * inv;
        o.y = O[i][1] * inv;
        o.z = O[i][2] * inv;
        o.w = O[i][3] * inv;
        *reinterpret_cast<float4*>(
            &out[((size_t)b * 2048 + qt * 64 + r0 + i) * 512 + h * 64 + c0]) = o;
    }
}

extern "C" void kernel_launch(void* const* d_in, const int* in_sizes, int n_in,
                              void* d_out, int out_size, void* d_ws, size_t ws_size,
                              hipStream_t stream)
{
    const float* q    = (const float*)d_in[0];
    const float* k    = (const float*)d_in[1];
    const int*   mask = (const int*)  d_in[2];
    const float* Wq   = (const float*)d_in[3];
    const float* bq   = (const float*)d_in[4];
    const float* Wk   = (const float*)d_in[5];
    const float* bk   = (const float*)d_in[6];
    const float* Wv   = (const float*)d_in[7];
    const float* bv   = (const float*)d_in[8];
    float* out = (float*)d_out;

    float* qh = (float*)d_ws;                      // [2,8,2048,64]  8MB
    float* kh = qh + (size_t)2 * 8 * 2048 * 64;    // [2,8,4096,64] 16MB
    float* vh = kh + (size_t)2 * 8 * 4096 * 64;    // [2,8,4096,64] 16MB

    dim3 blk(256);
    proj_kernel<<<dim3(8,  64), blk, 0, stream>>>(q, Wq, bq, qh, 2048);
    proj_kernel<<<dim3(8, 128), blk, 0, stream>>>(k, Wk, bk, kh, 4096);
    proj_kernel<<<dim3(8, 128), blk, 0, stream>>>(k, Wv, bv, vh, 4096);
    attn_kernel<<<dim3(32, 8, 2), blk, 0, stream>>>(qh, kh, vh, mask, out);
}

// Round 2
// 303.309 us; speedup vs baseline: 2.4966x; 2.4966x over previous
//
#include <hip/hip_runtime.h>
#include <hip/hip_bf16.h>

// R2: attention on bf16 MFMA (16x16x32), projections fp32 -> bf16 outputs.
// ws layout (bf16): qh [2,8,2048,64] 4MB | kh [2,8,4096,64] 8MB | vt [2,8,64,4096] 8MB

typedef short  s16x8 __attribute__((ext_vector_type(8)));
typedef short  s16x4 __attribute__((ext_vector_type(4)));
typedef float  f32x4 __attribute__((ext_vector_type(4)));

__device__ __forceinline__ unsigned short f2bf(float x) {
    return __builtin_bit_cast(unsigned short, __float2bfloat16(x));
}

// ---------------- projection: C = A @ W + bias -----------------------------
// TRANS=0: dst[b, h, s, w] bf16.  TRANS=1: dst[b, h, w, s] bf16 (for V).
template <int TRANS>
__global__ __launch_bounds__(256) void proj_kernel(
    const float* __restrict__ A,    // [B*S, 512]
    const float* __restrict__ Wm,   // [512, 512]
    const float* __restrict__ bias, // [512]
    unsigned short* __restrict__ dst,
    int S)
{
    __shared__ float As[32][68];
    __shared__ float Bs[32][68];

    const int tid = threadIdx.x;
    const int m0 = blockIdx.y * 64;
    const int n0 = blockIdx.x * 64;
    const int g  = tid >> 4;
    const int cg = tid & 15;
    const int r0 = g * 4, c0 = cg * 4;

    const int arow = tid >> 3;
    const int akc  = (tid & 7) << 2;
    const int bkk  = tid >> 4;
    const int bc4  = (tid & 15) << 2;

    float acc[4][4];
    #pragma unroll
    for (int i = 0; i < 4; ++i)
        #pragma unroll
        for (int j = 0; j < 4; ++j) acc[i][j] = 0.f;

    for (int k0 = 0; k0 < 512; k0 += 32) {
        __syncthreads();
        #pragma unroll
        for (int pass = 0; pass < 2; ++pass) {
            int rr = arow + pass * 32;
            float4 v = *reinterpret_cast<const float4*>(
                &A[(size_t)(m0 + rr) * 512 + k0 + akc]);
            As[akc + 0][rr] = v.x;
            As[akc + 1][rr] = v.y;
            As[akc + 2][rr] = v.z;
            As[akc + 3][rr] = v.w;
            int kr = bkk + pass * 16;
            *reinterpret_cast<float4*>(&Bs[kr][bc4]) =
                *reinterpret_cast<const float4*>(
                    &Wm[(size_t)(k0 + kr) * 512 + n0 + bc4]);
        }
        __syncthreads();
        #pragma unroll
        for (int kk = 0; kk < 32; ++kk) {
            float4 a4 = *reinterpret_cast<const float4*>(&As[kk][r0]);
            float4 b4 = *reinterpret_cast<const float4*>(&Bs[kk][c0]);
            float a[4] = {a4.x, a4.y, a4.z, a4.w};
            float b[4] = {b4.x, b4.y, b4.z, b4.w};
            #pragma unroll
            for (int i = 0; i < 4; ++i)
                #pragma unroll
                for (int j = 0; j < 4; ++j)
                    acc[i][j] = fmaf(a[i], b[j], acc[i][j]);
        }
    }

    const int hh = n0 >> 6;
    const int b  = m0 / S;
    const int s0 = m0 - b * S;
    float4 bb4 = *reinterpret_cast<const float4*>(&bias[n0 + c0]);
    float bb[4] = {bb4.x, bb4.y, bb4.z, bb4.w};

    if constexpr (!TRANS) {
        #pragma unroll
        for (int i = 0; i < 4; ++i) {
            s16x4 o;
            #pragma unroll
            for (int j = 0; j < 4; ++j)
                o[j] = (short)f2bf(acc[i][j] + bb[j]);
            *reinterpret_cast<s16x4*>(
                &dst[(((size_t)b * 8 + hh) * S + (s0 + r0 + i)) * 64 + c0]) = o;
        }
    } else {
        __shared__ unsigned short Ts[64 * 72];   // [w][key], key-dim padded
        #pragma unroll
        for (int i = 0; i < 4; ++i)
            #pragma unroll
            for (int j = 0; j < 4; ++j)
                Ts[(c0 + j) * 72 + (r0 + i)] = f2bf(acc[i][j] + bb[j]);
        __syncthreads();
        const int w  = tid >> 2;
        const int kc = (tid & 3) * 16;
        s16x8 v0 = *reinterpret_cast<const s16x8*>(&Ts[w * 72 + kc]);
        s16x8 v1 = *reinterpret_cast<const s16x8*>(&Ts[w * 72 + kc + 8]);
        unsigned short* dp =
            &dst[(((size_t)b * 8 + hh) * 64 + w) * (size_t)S + s0 + kc];
        *reinterpret_cast<s16x8*>(dp)     = v0;
        *reinterpret_cast<s16x8*>(dp + 8) = v1;
    }
}

// ---------------- fused attention, bf16 MFMA -------------------------------
__global__ __launch_bounds__(256) void attn_mfma(
    const unsigned short* __restrict__ qh,  // [B,8,2048,64] bf16
    const unsigned short* __restrict__ kh,  // [B,8,4096,64] bf16
    const unsigned short* __restrict__ vt,  // [B,8,64,4096] bf16 (V^T)
    const int*            __restrict__ mask,// [B,4096]
    float* __restrict__ out)                // [B,2048,512]
{
    __shared__ unsigned short Ks[64 * 64];   // [key][w], swizzled
    __shared__ unsigned short Vs[64 * 64];   // [w][key], swizzled
    __shared__ unsigned short Pl[4 * 16 * 64]; // per-wave P [q][key], swizzled
    __shared__ float msk[64];

    const int tid  = threadIdx.x;
    const int wv   = tid >> 6;
    const int lane = tid & 63;
    const int g    = lane >> 4;
    const int ln   = lane & 15;

    const int qt = blockIdx.x;
    const int h  = blockIdx.y;
    const int b  = blockIdx.z;
    const int bh = b * 8 + h;

    const unsigned short* Kg = kh + (size_t)bh * 4096 * 64;
    const unsigned short* Vg = vt + (size_t)bh * 64 * 4096;
    const unsigned short* Qg = qh + ((size_t)bh * 2048 + qt * 64 + wv * 16) * 64;

    // Q fragments (A operand): row = ln, k = 8g+j (+32 per kstep)
    s16x8 aq[2];
    #pragma unroll
    for (int ks = 0; ks < 2; ++ks)
        aq[ks] = *reinterpret_cast<const s16x8*>(&Qg[ln * 64 + ks * 32 + g * 8]);

    f32x4 Ot[4];
    float m_run[4], l_run[4];
    #pragma unroll
    for (int t = 0; t < 4; ++t) Ot[t] = (f32x4)0.f;
    #pragma unroll
    for (int r = 0; r < 4; ++r) { m_run[r] = -1e30f; l_run[r] = 0.f; }

    for (int kt = 0; kt < 4096; kt += 64) {
        __syncthreads();
        // stage K tile [64 key][64 w] and V^T tile [64 w][64 key], swizzled
        #pragma unroll
        for (int p = 0; p < 2; ++p) {
            int c   = tid + p * 256;
            int row = c >> 3;
            int cb  = (c & 7) * 8;
            int phys = (row * 64 + cb) ^ ((row & 7) << 3);
            *reinterpret_cast<s16x8*>(&Ks[phys]) =
                *reinterpret_cast<const s16x8*>(&Kg[(size_t)(kt + row) * 64 + cb]);
            *reinterpret_cast<s16x8*>(&Vs[phys]) =
                *reinterpret_cast<const s16x8*>(&Vg[(size_t)row * 4096 + kt + cb]);
        }
        if (tid < 64)
            msk[tid] = -10000.f * (1.f - (float)mask[b * 4096 + kt + tid]);
        __syncthreads();

        // S = Q K^T : B operand from Ks (col = key = ln+16t, k = w)
        f32x4 s4[4];
        #pragma unroll
        for (int t = 0; t < 4; ++t) s4[t] = (f32x4)0.f;
        #pragma unroll
        for (int t = 0; t < 4; ++t) {
            int row = ln + 16 * t;
            #pragma unroll
            for (int ks = 0; ks < 2; ++ks) {
                int phys = (row * 64 + ks * 32 + g * 8) ^ ((row & 7) << 3);
                s16x8 kb = *reinterpret_cast<const s16x8*>(&Ks[phys]);
                s4[t] = __builtin_amdgcn_mfma_f32_16x16x32_bf16(aq[ks], kb, s4[t], 0, 0, 0);
            }
        }

        // online softmax; write P (bf16) to wave-private LDS
        #pragma unroll
        for (int r = 0; r < 4; ++r) {
            float sv[4];
            #pragma unroll
            for (int t = 0; t < 4; ++t)
                sv[t] = fmaf(s4[t][r], 0.125f, msk[ln + 16 * t]);
            float mx = fmaxf(fmaxf(sv[0], sv[1]), fmaxf(sv[2], sv[3]));
            mx = fmaxf(mx, __shfl_xor(mx, 1));
            mx = fmaxf(mx, __shfl_xor(mx, 2));
            mx = fmaxf(mx, __shfl_xor(mx, 4));
            mx = fmaxf(mx, __shfl_xor(mx, 8));
            float mnew = fmaxf(m_run[r], mx);
            float sc = __expf(m_run[r] - mnew);
            m_run[r] = mnew;
            int prow = 4 * g + r;
            float rs = 0.f;
            #pragma unroll
            for (int t = 0; t < 4; ++t) {
                float p = __expf(sv[t] - mnew);
                rs += p;
                int phys = (prow * 64 + ln + 16 * t) ^ ((prow & 7) << 3);
                Pl[wv * 1024 + phys] = f2bf(p);
            }
            rs += __shfl_xor(rs, 1);
            rs += __shfl_xor(rs, 2);
            rs += __shfl_xor(rs, 4);
            rs += __shfl_xor(rs, 8);
            l_run[r] = l_run[r] * sc + rs;
            #pragma unroll
            for (int t = 0; t < 4; ++t) Ot[t][r] *= sc;
        }

        // O += P @ V : A from Pl (row = ln), B from Vs (col = w = ln+16t)
        s16x8 pa[2];
        #pragma unroll
        for (int ks = 0; ks < 2; ++ks) {
            int phys = (ln * 64 + ks * 32 + g * 8) ^ ((ln & 7) << 3);
            pa[ks] = *reinterpret_cast<const s16x8*>(&Pl[wv * 1024 + phys]);
        }
        #pragma unroll
        for (int t = 0; t < 4; ++t) {
            int row = ln + 16 * t;
            #pragma unroll
            for (int ks = 0; ks < 2; ++ks) {
                int phys = (row * 64 + ks * 32 + g * 8) ^ ((row & 7) << 3);
                s16x8 vb = *reinterpret_cast<const s16x8*>(&Vs[phys]);
                Ot[t] = __builtin_amdgcn_mfma_f32_16x16x32_bf16(pa[ks], vb, Ot[t], 0, 0, 0);
            }
        }
    }

    #pragma unroll
    for (int r = 0; r < 4; ++r) {
        float inv = 1.f / l_run[r];
        int q = qt * 64 + wv * 16 + 4 * g + r;
        #pragma unroll
        for (int t = 0; t < 4; ++t)
            out[((size_t)b * 2048 + q) * 512 + h * 64 + ln + 16 * t] = Ot[t][r] * inv;
    }
}

extern "C" void kernel_launch(void* const* d_in, const int* in_sizes, int n_in,
                              void* d_out, int out_size, void* d_ws, size_t ws_size,
                              hipStream_t stream)
{
    const float* q    = (const float*)d_in[0];
    const float* k    = (const float*)d_in[1];
    const int*   mask = (const int*)  d_in[2];
    const float* Wq   = (const float*)d_in[3];
    const float* bq   = (const float*)d_in[4];
    const float* Wk   = (const float*)d_in[5];
    const float* bk   = (const float*)d_in[6];
    const float* Wv   = (const float*)d_in[7];
    const float* bv   = (const float*)d_in[8];
    float* out = (float*)d_out;

    unsigned short* qh = (unsigned short*)d_ws;                  // 2*8*2048*64
    unsigned short* kh = qh + (size_t)2 * 8 * 2048 * 64;         // 2*8*4096*64
    unsigned short* vt = kh + (size_t)2 * 8 * 4096 * 64;         // 2*8*64*4096

    dim3 blk(256);
    proj_kernel<0><<<dim3(8,  64), blk, 0, stream>>>(q, Wq, bq, qh, 2048);
    proj_kernel<0><<<dim3(8, 128), blk, 0, stream>>>(k, Wk, bk, kh, 4096);
    proj_kernel<1><<<dim3(8, 128), blk, 0, stream>>>(k, Wv, bv, vt, 4096);
    attn_mfma<<<dim3(32, 8, 2), blk, 0, stream>>>(qh, kh, vt, mask, out);
}

// Round 3
// 136.075 us; speedup vs baseline: 5.5650x; 2.2290x over previous
//
#include <hip/hip_runtime.h>
#include <hip/hip_bf16.h>

// R3: bf16-MFMA projections (pre-cast inputs/weights) + no-max swapped-QK
// flash attention. All LDS tiles XOR-swizzled (byte ^= (row&7)<<4), staged
// via global_load_lds with pre-swizzled global source (linear LDS dest).

typedef short  s16x8 __attribute__((ext_vector_type(8)));
typedef short  s16x4 __attribute__((ext_vector_type(4)));
typedef float  f32x4 __attribute__((ext_vector_type(4)));

__device__ __forceinline__ unsigned short f2bf(float x) {
    return __builtin_bit_cast(unsigned short, __float2bfloat16(x));
}

__device__ __forceinline__ void gload16(const void* g, void* lds) {
    __builtin_amdgcn_global_load_lds(
        (const __attribute__((address_space(1))) unsigned int*)g,
        (__attribute__((address_space(3))) unsigned int*)lds,
        16, 0, 0);
}

// ---------------- cast fp32 -> bf16, 8 elems/thread ------------------------
__global__ __launch_bounds__(256) void cast_bf16(
    const float* __restrict__ src, unsigned short* __restrict__ dst, int n8)
{
    int i = blockIdx.x * 256 + threadIdx.x;
    if (i >= n8) return;
    float4 a = reinterpret_cast<const float4*>(src)[2 * i];
    float4 b = reinterpret_cast<const float4*>(src)[2 * i + 1];
    s16x8 o;
    o[0] = (short)f2bf(a.x); o[1] = (short)f2bf(a.y);
    o[2] = (short)f2bf(a.z); o[3] = (short)f2bf(a.w);
    o[4] = (short)f2bf(b.x); o[5] = (short)f2bf(b.y);
    o[6] = (short)f2bf(b.z); o[7] = (short)f2bf(b.w);
    reinterpret_cast<s16x8*>(dst)[i] = o;
}

// ---------------- transpose + cast W [k][n] fp32 -> Wt [n][k] bf16 ---------
__global__ __launch_bounds__(256) void transW(
    const float* __restrict__ W0, const float* __restrict__ W1,
    const float* __restrict__ W2,
    unsigned short* __restrict__ D0, unsigned short* __restrict__ D1,
    unsigned short* __restrict__ D2)
{
    const float* W = blockIdx.z == 0 ? W0 : blockIdx.z == 1 ? W1 : W2;
    unsigned short* D = blockIdx.z == 0 ? D0 : blockIdx.z == 1 ? D1 : D2;
    __shared__ float T[64][65];
    const int tid = threadIdx.x;
    const int k0 = blockIdx.y * 64, n0 = blockIdx.x * 64;
    const int r = tid >> 2, cq = tid & 3;
    #pragma unroll
    for (int p = 0; p < 4; ++p) {
        int c = (cq + 4 * p) * 4;
        float4 v = *reinterpret_cast<const float4*>(&W[(size_t)(k0 + r) * 512 + n0 + c]);
        T[c + 0][r] = v.x; T[c + 1][r] = v.y;
        T[c + 2][r] = v.z; T[c + 3][r] = v.w;
    }
    __syncthreads();
    #pragma unroll
    for (int p = 0; p < 4; ++p) {
        int kc = (cq + 4 * p) * 4;
        s16x4 o;
        o[0] = (short)f2bf(T[r][kc + 0]);
        o[1] = (short)f2bf(T[r][kc + 1]);
        o[2] = (short)f2bf(T[r][kc + 2]);
        o[3] = (short)f2bf(T[r][kc + 3]);
        *reinterpret_cast<s16x4*>(&D[(size_t)(n0 + r) * 512 + k0 + kc]) = o;
    }
}

// ---------------- projection GEMM, bf16 MFMA -------------------------------
// TRANS=0: dst[b,h,s,w] = A@W + bias.  TRANS=1: dst[b,h,w,s] (V^T), computed
// as C^T = Wt-rows x A-rows via swapped mfma operands.
template <int TRANS>
__global__ __launch_bounds__(256) void proj2(
    const unsigned short* __restrict__ Abf, // [B*S, 512] bf16
    const unsigned short* __restrict__ Wt,  // [512 n][512 k] bf16
    const float* __restrict__ bias,         // [512]
    unsigned short* __restrict__ dst, int S)
{
    __shared__ unsigned short As[128 * 64]; // [s][k] swizzled
    __shared__ unsigned short Bs[64 * 64];  // [n][k] swizzled

    const int tid  = threadIdx.x;
    const int wv   = tid >> 6;
    const int lane = tid & 63;
    const int g    = lane >> 4;
    const int ln   = lane & 15;
    const int swz  = (ln & 7) << 3;

    const int m0 = blockIdx.y * 128;
    const int n0 = blockIdx.x * 64;

    f32x4 acc[4][2];
    #pragma unroll
    for (int i = 0; i < 4; ++i)
        #pragma unroll
        for (int j = 0; j < 2; ++j) acc[i][j] = (f32x4)0.f;

    for (int k0 = 0; k0 < 512; k0 += 64) {
        __syncthreads();
        #pragma unroll
        for (int p = 0; p < 4; ++p) {
            int slot = p * 256 + tid;
            int row = slot >> 3, cb = slot & 7;
            int cbp = cb ^ (row & 7);
            gload16(&Abf[(size_t)(m0 + row) * 512 + k0 + cbp * 8], &As[slot * 8]);
        }
        #pragma unroll
        for (int p = 0; p < 2; ++p) {
            int slot = p * 256 + tid;
            int row = slot >> 3, cb = slot & 7;
            int cbp = cb ^ (row & 7);
            gload16(&Wt[(size_t)(n0 + row) * 512 + k0 + cbp * 8], &Bs[slot * 8]);
        }
        __syncthreads();
        #pragma unroll
        for (int ks = 0; ks < 2; ++ks) {
            if constexpr (!TRANS) {
                s16x8 a[2], bf[4];
                #pragma unroll
                for (int mi = 0; mi < 2; ++mi)
                    a[mi] = *reinterpret_cast<const s16x8*>(
                        &As[((wv * 32 + 16 * mi + ln) * 64 + ks * 32 + g * 8) ^ swz]);
                #pragma unroll
                for (int nj = 0; nj < 4; ++nj)
                    bf[nj] = *reinterpret_cast<const s16x8*>(
                        &Bs[((16 * nj + ln) * 64 + ks * 32 + g * 8) ^ swz]);
                #pragma unroll
                for (int mi = 0; mi < 2; ++mi)
                    #pragma unroll
                    for (int nj = 0; nj < 4; ++nj)
                        acc[nj][mi] = __builtin_amdgcn_mfma_f32_16x16x32_bf16(
                            a[mi], bf[nj], acc[nj][mi], 0, 0, 0);
            } else {
                s16x8 w[4], a[2];
                #pragma unroll
                for (int mi = 0; mi < 4; ++mi)
                    w[mi] = *reinterpret_cast<const s16x8*>(
                        &Bs[((16 * mi + ln) * 64 + ks * 32 + g * 8) ^ swz]);
                #pragma unroll
                for (int sj = 0; sj < 2; ++sj)
                    a[sj] = *reinterpret_cast<const s16x8*>(
                        &As[((wv * 32 + 16 * sj + ln) * 64 + ks * 32 + g * 8) ^ swz]);
                #pragma unroll
                for (int mi = 0; mi < 4; ++mi)
                    #pragma unroll
                    for (int sj = 0; sj < 2; ++sj)
                        acc[mi][sj] = __builtin_amdgcn_mfma_f32_16x16x32_bf16(
                            w[mi], a[sj], acc[mi][sj], 0, 0, 0);
            }
        }
    }

    const int h    = n0 >> 6;
    const int bidx = m0 / S;
    const int s0   = m0 - bidx * S;

    if constexpr (!TRANS) {
        float bv[4];
        #pragma unroll
        for (int nj = 0; nj < 4; ++nj) bv[nj] = bias[n0 + 16 * nj + ln];
        unsigned short* base = dst + ((size_t)(bidx * 8 + h) * S) * 64;
        #pragma unroll
        for (int mi = 0; mi < 2; ++mi)
            #pragma unroll
            for (int r = 0; r < 4; ++r) {
                int s = s0 + wv * 32 + 16 * mi + 4 * g + r;
                #pragma unroll
                for (int nj = 0; nj < 4; ++nj)
                    base[(size_t)s * 64 + 16 * nj + ln] =
                        f2bf(acc[nj][mi][r] + bv[nj]);
            }
    } else {
        unsigned short* base = dst + ((size_t)(bidx * 8 + h) * 64) * (size_t)S;
        #pragma unroll
        for (int mi = 0; mi < 4; ++mi)
            #pragma unroll
            for (int r = 0; r < 4; ++r) {
                int w = 16 * mi + 4 * g + r;
                float bw = bias[n0 + w];
                #pragma unroll
                for (int sj = 0; sj < 2; ++sj)
                    base[(size_t)w * S + s0 + wv * 32 + 16 * sj + ln] =
                        f2bf(acc[mi][sj][r] + bw);
            }
    }
}

// ---------------- fused attention: swapped QK^T, no-max softmax ------------
__global__ __launch_bounds__(256) void attn2(
    const unsigned short* __restrict__ qh,  // [B,8,2048,64] bf16
    const unsigned short* __restrict__ kh,  // [B,8,4096,64] bf16
    const unsigned short* __restrict__ vt,  // [B,8,64,4096] bf16 (V^T)
    const int*            __restrict__ mask,// [B,4096]
    float* __restrict__ out)                // [B,2048,512]
{
    __shared__ unsigned short Ks[64 * 64];     // [key][w] swizzled
    __shared__ unsigned short Vs[64 * 64];     // [w][key] swizzled
    __shared__ unsigned short Pl[4 * 16 * 64]; // per-wave P [q][key] swizzled
    __shared__ float msk[64];

    const int tid  = threadIdx.x;
    const int wv   = tid >> 6;
    const int lane = tid & 63;
    const int g    = lane >> 4;
    const int ln   = lane & 15;
    const int swz  = (ln & 7) << 3;

    const int qt = blockIdx.x;
    const int h  = blockIdx.y;
    const int b  = blockIdx.z;
    const int bh = b * 8 + h;

    const unsigned short* Kg = kh + (size_t)bh * 4096 * 64;
    const unsigned short* Vg = vt + (size_t)bh * 64 * 4096;
    const unsigned short* Qg = qh + ((size_t)bh * 2048 + qt * 64 + wv * 16) * 64;

    // Q as B operand: col = ln (q-row), k contiguous
    s16x8 bq[2];
    #pragma unroll
    for (int ks = 0; ks < 2; ++ks)
        bq[ks] = *reinterpret_cast<const s16x8*>(&Qg[ln * 64 + ks * 32 + g * 8]);

    f32x4 Ot[4];
    #pragma unroll
    for (int t = 0; t < 4; ++t) Ot[t] = (f32x4)0.f;
    float l_part = 0.f;

    for (int kt = 0; kt < 4096; kt += 64) {
        __syncthreads();
        #pragma unroll
        for (int p = 0; p < 2; ++p) {
            int slot = p * 256 + tid;
            int row = slot >> 3, cb = slot & 7;
            int cbp = cb ^ (row & 7);
            gload16(&Kg[(size_t)(kt + row) * 64 + cbp * 8], &Ks[slot * 8]);
            gload16(&Vg[(size_t)row * 4096 + kt + cbp * 8], &Vs[slot * 8]);
        }
        if (tid < 64)
            msk[tid] = -14426.950408889634f * (1.f - (float)mask[b * 4096 + kt + tid]);
        __syncthreads();

        // S^T = K Q^T : rows = keys (4g+r+16t), cols = q (ln)
        f32x4 s4[4];
        #pragma unroll
        for (int t = 0; t < 4; ++t) s4[t] = (f32x4)0.f;
        #pragma unroll
        for (int t = 0; t < 4; ++t) {
            int row = ln + 16 * t;
            #pragma unroll
            for (int ks = 0; ks < 2; ++ks) {
                s16x8 ka = *reinterpret_cast<const s16x8*>(
                    &Ks[(row * 64 + ks * 32 + g * 8) ^ swz]);
                s4[t] = __builtin_amdgcn_mfma_f32_16x16x32_bf16(ka, bq[ks], s4[t], 0, 0, 0);
            }
        }

        // no-max softmax: P = exp2(s*log2e/8 + mask*log2e); packed b64 writes
        #pragma unroll
        for (int t = 0; t < 4; ++t) {
            float4 mv = *reinterpret_cast<const float4*>(&msk[16 * t + 4 * g]);
            float p0 = exp2f(fmaf(s4[t][0], 0.18033688011112042f, mv.x));
            float p1 = exp2f(fmaf(s4[t][1], 0.18033688011112042f, mv.y));
            float p2 = exp2f(fmaf(s4[t][2], 0.18033688011112042f, mv.z));
            float p3 = exp2f(fmaf(s4[t][3], 0.18033688011112042f, mv.w));
            l_part += (p0 + p1) + (p2 + p3);
            s16x4 pk;
            pk[0] = (short)f2bf(p0); pk[1] = (short)f2bf(p1);
            pk[2] = (short)f2bf(p2); pk[3] = (short)f2bf(p3);
            *reinterpret_cast<s16x4*>(
                &Pl[wv * 1024 + ((ln * 64 + 16 * t + 4 * g) ^ swz)]) = pk;
        }

        // O += P @ V : A = P (rows q), B = V^T tile (cols w)
        s16x8 pa[2];
        #pragma unroll
        for (int ks = 0; ks < 2; ++ks)
            pa[ks] = *reinterpret_cast<const s16x8*>(
                &Pl[wv * 1024 + ((ln * 64 + ks * 32 + g * 8) ^ swz)]);
        #pragma unroll
        for (int t = 0; t < 4; ++t) {
            int row = ln + 16 * t;
            #pragma unroll
            for (int ks = 0; ks < 2; ++ks) {
                s16x8 vb = *reinterpret_cast<const s16x8*>(
                    &Vs[(row * 64 + ks * 32 + g * 8) ^ swz]);
                Ot[t] = __builtin_amdgcn_mfma_f32_16x16x32_bf16(pa[ks], vb, Ot[t], 0, 0, 0);
            }
        }
    }

    // finish: reduce l across the 4 g-lanes holding each q-row
    l_part += __shfl_xor(l_part, 16);
    l_part += __shfl_xor(l_part, 32);
    #pragma unroll
    for (int r = 0; r < 4; ++r) {
        float lr  = __shfl(l_part, 4 * g + r);
        float inv = 1.f / lr;
        int q = qt * 64 + wv * 16 + 4 * g + r;
        #pragma unroll
        for (int t = 0; t < 4; ++t)
            out[((size_t)b * 2048 + q) * 512 + h * 64 + ln + 16 * t] = Ot[t][r] * inv;
    }
}

extern "C" void kernel_launch(void* const* d_in, const int* in_sizes, int n_in,
                              void* d_out, int out_size, void* d_ws, size_t ws_size,
                              hipStream_t stream)
{
    const float* q    = (const float*)d_in[0];
    const float* k    = (const float*)d_in[1];
    const int*   mask = (const int*)  d_in[2];
    const float* Wq   = (const float*)d_in[3];
    const float* bq   = (const float*)d_in[4];
    const float* Wk   = (const float*)d_in[5];
    const float* bk   = (const float*)d_in[6];
    const float* Wv   = (const float*)d_in[7];
    const float* bv   = (const float*)d_in[8];
    float* out = (float*)d_out;

    unsigned short* p = (unsigned short*)d_ws;
    unsigned short* qbf = p; p += (size_t)2 * 2048 * 512;   // 2M
    unsigned short* kbf = p; p += (size_t)2 * 4096 * 512;   // 4M
    unsigned short* wtq = p; p += 512 * 512;
    unsigned short* wtk = p; p += 512 * 512;
    unsigned short* wtv = p; p += 512 * 512;
    unsigned short* qh  = p; p += (size_t)2 * 8 * 2048 * 64;
    unsigned short* kh  = p; p += (size_t)2 * 8 * 4096 * 64;
    unsigned short* vt  = p; p += (size_t)2 * 8 * 64 * 4096;

    dim3 blk(256);
    cast_bf16<<<dim3(1024), blk, 0, stream>>>(q, qbf, 2 * 2048 * 512 / 8);
    cast_bf16<<<dim3(2048), blk, 0, stream>>>(k, kbf, 2 * 4096 * 512 / 8);
    transW<<<dim3(8, 8, 3), blk, 0, stream>>>(Wq, Wk, Wv, wtq, wtk, wtv);

    proj2<0><<<dim3(8, 32), blk, 0, stream>>>(qbf, wtq, bq, qh, 2048);
    proj2<0><<<dim3(8, 64), blk, 0, stream>>>(kbf, wtk, bk, kh, 4096);
    proj2<1><<<dim3(8, 64), blk, 0, stream>>>(kbf, wtv, bv, vt, 4096);

    attn2<<<dim3(32, 8, 2), blk, 0, stream>>>(qh, kh, vt, mask, out);
}

// Round 4
// 128.465 us; speedup vs baseline: 5.8947x; 1.0592x over previous
//
#include <hip/hip_runtime.h>
#include <hip/hip_bf16.h>

// R4: 2-phase pipelined staging everywhere (stage-ahead + single barrier/tile),
// split-KV x2 attention with exact no-max partial-softmax combine, fused
// prep (cast+transposeW) and fused 3-in-1 projection kernel.
// ws (elems): qh 4MB | kh 8MB | vt 8MB | { qbf 4MB | kbf 8MB | wt 1.5MB }
//                                        aliased by { OP 16.8MB | lp 256KB }

typedef short  s16x8 __attribute__((ext_vector_type(8)));
typedef short  s16x4 __attribute__((ext_vector_type(4)));
typedef float  f32x4 __attribute__((ext_vector_type(4)));

__device__ __forceinline__ unsigned short f2bf(float x) {
    return __builtin_bit_cast(unsigned short, __float2bfloat16(x));
}
__device__ __forceinline__ void gload16(const void* g, void* lds) {
    __builtin_amdgcn_global_load_lds(
        (const __attribute__((address_space(1))) unsigned int*)g,
        (__attribute__((address_space(3))) unsigned int*)lds, 16, 0, 0);
}

// ---------------- prep: cast q,k to bf16 + transpose/cast W ----------------
__global__ __launch_bounds__(256) void prep(
    const float* __restrict__ q, const float* __restrict__ k,
    const float* __restrict__ Wq, const float* __restrict__ Wk,
    const float* __restrict__ Wv,
    unsigned short* __restrict__ qbf, unsigned short* __restrict__ kbf,
    unsigned short* __restrict__ wtq, unsigned short* __restrict__ wtk,
    unsigned short* __restrict__ wtv)
{
    __shared__ float T[64][65];
    const int bid = blockIdx.x;
    const int tid = threadIdx.x;
    if (bid < 3072) {
        const float* src = bid < 1024 ? q : k;
        unsigned short* dst = bid < 1024 ? qbf : kbf;
        int i = (bid < 1024 ? bid : bid - 1024) * 256 + tid;
        float4 a = reinterpret_cast<const float4*>(src)[2 * i];
        float4 b = reinterpret_cast<const float4*>(src)[2 * i + 1];
        s16x8 o;
        o[0] = (short)f2bf(a.x); o[1] = (short)f2bf(a.y);
        o[2] = (short)f2bf(a.z); o[3] = (short)f2bf(a.w);
        o[4] = (short)f2bf(b.x); o[5] = (short)f2bf(b.y);
        o[6] = (short)f2bf(b.z); o[7] = (short)f2bf(b.w);
        reinterpret_cast<s16x8*>(dst)[i] = o;
    } else {
        int t = bid - 3072;                 // 0..191
        int z = t >> 6;
        int tt = t & 63;
        const float* W = z == 0 ? Wq : z == 1 ? Wk : Wv;
        unsigned short* D = z == 0 ? wtq : z == 1 ? wtk : wtv;
        const int k0 = (tt >> 3) * 64, n0 = (tt & 7) * 64;
        const int r = tid >> 2, cq = tid & 3;
        #pragma unroll
        for (int p = 0; p < 4; ++p) {
            int c = (cq + 4 * p) * 4;
            float4 v = *reinterpret_cast<const float4*>(
                &W[(size_t)(k0 + r) * 512 + n0 + c]);
            T[c + 0][r] = v.x; T[c + 1][r] = v.y;
            T[c + 2][r] = v.z; T[c + 3][r] = v.w;
        }
        __syncthreads();
        #pragma unroll
        for (int p = 0; p < 4; ++p) {
            int kc = (cq + 4 * p) * 4;
            s16x4 o;
            o[0] = (short)f2bf(T[r][kc + 0]);
            o[1] = (short)f2bf(T[r][kc + 1]);
            o[2] = (short)f2bf(T[r][kc + 2]);
            o[3] = (short)f2bf(T[r][kc + 3]);
            *reinterpret_cast<s16x4*>(&D[(size_t)(n0 + r) * 512 + k0 + kc]) = o;
        }
    }
}

// ---------------- fused 3-way projection GEMM, bf16 MFMA, 2-phase ----------
__global__ __launch_bounds__(256) void proj3(
    const unsigned short* __restrict__ qbf, const unsigned short* __restrict__ kbf,
    const unsigned short* __restrict__ wtq, const unsigned short* __restrict__ wtk,
    const unsigned short* __restrict__ wtv,
    const float* __restrict__ bq, const float* __restrict__ bk,
    const float* __restrict__ bv,
    unsigned short* __restrict__ qh, unsigned short* __restrict__ kh,
    unsigned short* __restrict__ vt)
{
    __shared__ unsigned short As[2][128 * 64];
    __shared__ unsigned short Bs[2][64 * 64];

    const int tid  = threadIdx.x;
    const int wv   = tid >> 6;
    const int lane = tid & 63;
    const int g    = lane >> 4;
    const int ln   = lane & 15;
    const int swz  = (ln & 7) << 3;

    const int id = blockIdx.x;
    const unsigned short *A, *Wt;
    const float* bias;
    unsigned short* dst;
    int S, trans, nb, mb;
    if (id < 256)      { A = qbf; Wt = wtq; bias = bq; dst = qh; S = 2048; trans = 0; nb = id & 7;         mb = id >> 3; }
    else if (id < 768) { A = kbf; Wt = wtk; bias = bk; dst = kh; S = 4096; trans = 0; nb = (id - 256) & 7; mb = (id - 256) >> 3; }
    else               { A = kbf; Wt = wtv; bias = bv; dst = vt; S = 4096; trans = 1; nb = (id - 768) & 7; mb = (id - 768) >> 3; }
    const int m0 = mb * 128, n0 = nb * 64;

    f32x4 acc[4][2];
    #pragma unroll
    for (int i = 0; i < 4; ++i)
        #pragma unroll
        for (int j = 0; j < 2; ++j) acc[i][j] = (f32x4)0.f;

    auto stage = [&](int bufn, int k0) {
        #pragma unroll
        for (int p = 0; p < 4; ++p) {
            int slot = p * 256 + tid;
            int row = slot >> 3, cb = slot & 7;
            int cbp = cb ^ (row & 7);
            gload16(&A[(size_t)(m0 + row) * 512 + k0 + cbp * 8], &As[bufn][slot * 8]);
        }
        #pragma unroll
        for (int p = 0; p < 2; ++p) {
            int slot = p * 256 + tid;
            int row = slot >> 3, cb = slot & 7;
            int cbp = cb ^ (row & 7);
            gload16(&Wt[(size_t)(n0 + row) * 512 + k0 + cbp * 8], &Bs[bufn][slot * 8]);
        }
    };

    stage(0, 0);
    __syncthreads();
    int buf = 0;
    for (int kk = 0; kk < 8; ++kk) {
        if (kk < 7) stage(buf ^ 1, (kk + 1) * 64);
        #pragma unroll
        for (int ks = 0; ks < 2; ++ks) {
            s16x8 fa[2], fb[4];
            #pragma unroll
            for (int mi = 0; mi < 2; ++mi)
                fa[mi] = *reinterpret_cast<const s16x8*>(
                    &As[buf][((wv * 32 + 16 * mi + ln) * 64 + ks * 32 + g * 8) ^ swz]);
            #pragma unroll
            for (int nj = 0; nj < 4; ++nj)
                fb[nj] = *reinterpret_cast<const s16x8*>(
                    &Bs[buf][((16 * nj + ln) * 64 + ks * 32 + g * 8) ^ swz]);
            if (!trans) {
                #pragma unroll
                for (int mi = 0; mi < 2; ++mi)
                    #pragma unroll
                    for (int nj = 0; nj < 4; ++nj)
                        acc[nj][mi] = __builtin_amdgcn_mfma_f32_16x16x32_bf16(
                            fa[mi], fb[nj], acc[nj][mi], 0, 0, 0);
            } else {
                #pragma unroll
                for (int nj = 0; nj < 4; ++nj)
                    #pragma unroll
                    for (int mi = 0; mi < 2; ++mi)
                        acc[nj][mi] = __builtin_amdgcn_mfma_f32_16x16x32_bf16(
                            fb[nj], fa[mi], acc[nj][mi], 0, 0, 0);
            }
        }
        __syncthreads();
        buf ^= 1;
    }

    const int h    = nb;
    const int bidx = m0 / S;
    const int s0   = m0 - bidx * S;

    if (!trans) {
        float bvv[4];
        #pragma unroll
        for (int nj = 0; nj < 4; ++nj) bvv[nj] = bias[n0 + 16 * nj + ln];
        unsigned short* base = dst + (size_t)(bidx * 8 + h) * S * 64;
        #pragma unroll
        for (int mi = 0; mi < 2; ++mi)
            #pragma unroll
            for (int r = 0; r < 4; ++r) {
                int s = s0 + wv * 32 + 16 * mi + 4 * g + r;
                #pragma unroll
                for (int nj = 0; nj < 4; ++nj)
                    base[(size_t)s * 64 + 16 * nj + ln] =
                        f2bf(acc[nj][mi][r] + bvv[nj]);
            }
    } else {
        unsigned short* base = dst + (size_t)(bidx * 8 + h) * 64 * (size_t)S;
        #pragma unroll
        for (int nj = 0; nj < 4; ++nj)
            #pragma unroll
            for (int r = 0; r < 4; ++r) {
                int w = 16 * nj + 4 * g + r;
                float bw = bias[n0 + w];
                #pragma unroll
                for (int mi = 0; mi < 2; ++mi)
                    base[(size_t)w * S + s0 + wv * 32 + 16 * mi + ln] =
                        f2bf(acc[nj][mi][r] + bw);
            }
    }
}

// ---------------- attention: split-KV x2, 2-phase pipeline -----------------
__global__ __launch_bounds__(256) void attn3(
    const unsigned short* __restrict__ qh,  // [B,8,2048,64] bf16
    const unsigned short* __restrict__ kh,  // [B,8,4096,64] bf16
    const unsigned short* __restrict__ vt,  // [B,8,64,4096] bf16 (V^T)
    const int*            __restrict__ mask,// [B,4096]
    float* __restrict__ OP,                 // [chunk 2][bh 16][q 2048][w 64]
    float* __restrict__ lp)                 // [chunk 2][bh 16][q 2048]
{
    __shared__ unsigned short Ks[2][64 * 64];
    __shared__ unsigned short Vs[2][64 * 64];
    __shared__ unsigned short Pl[4][16 * 64];
    __shared__ float msk[2][64];

    const int tid  = threadIdx.x;
    const int wv   = tid >> 6;
    const int lane = tid & 63;
    const int g    = lane >> 4;
    const int ln   = lane & 15;
    const int swz  = (ln & 7) << 3;

    const int qt    = blockIdx.x >> 1;
    const int chunk = blockIdx.x & 1;
    const int h  = blockIdx.y;
    const int b  = blockIdx.z;
    const int bh = b * 8 + h;
    const int kt0 = chunk * 2048;

    const unsigned short* Kg = kh + (size_t)bh * 4096 * 64;
    const unsigned short* Vg = vt + (size_t)bh * 64 * 4096;
    const unsigned short* Qg = qh + ((size_t)bh * 2048 + qt * 64 + wv * 16) * 64;

    s16x8 bq[2];
    #pragma unroll
    for (int ks = 0; ks < 2; ++ks)
        bq[ks] = *reinterpret_cast<const s16x8*>(&Qg[ln * 64 + ks * 32 + g * 8]);

    f32x4 Ot[4];
    #pragma unroll
    for (int t = 0; t < 4; ++t) Ot[t] = (f32x4)0.f;
    float l_part = 0.f;

    auto stage = [&](int bufn, int kt) {
        #pragma unroll
        for (int p = 0; p < 2; ++p) {
            int slot = p * 256 + tid;
            int row = slot >> 3, cb = slot & 7;
            int cbp = cb ^ (row & 7);
            gload16(&Kg[(size_t)(kt + row) * 64 + cbp * 8], &Ks[bufn][slot * 8]);
            gload16(&Vg[(size_t)row * 4096 + kt + cbp * 8], &Vs[bufn][slot * 8]);
        }
        if (tid < 64)
            msk[bufn][tid] =
                -14426.950408889634f * (1.f - (float)mask[b * 4096 + kt + tid]);
    };

    stage(0, kt0);
    __syncthreads();
    int buf = 0;
    for (int t = 0; t < 32; ++t) {
        if (t < 31) stage(buf ^ 1, kt0 + (t + 1) * 64);

        // S^T = K Q^T
        f32x4 s4[4];
        #pragma unroll
        for (int tt = 0; tt < 4; ++tt) s4[tt] = (f32x4)0.f;
        #pragma unroll
        for (int tt = 0; tt < 4; ++tt) {
            int row = ln + 16 * tt;
            #pragma unroll
            for (int ks = 0; ks < 2; ++ks) {
                s16x8 ka = *reinterpret_cast<const s16x8*>(
                    &Ks[buf][(row * 64 + ks * 32 + g * 8) ^ swz]);
                s4[tt] = __builtin_amdgcn_mfma_f32_16x16x32_bf16(ka, bq[ks], s4[tt], 0, 0, 0);
            }
        }

        // no-max softmax
        #pragma unroll
        for (int tt = 0; tt < 4; ++tt) {
            float4 mv = *reinterpret_cast<const float4*>(&msk[buf][16 * tt + 4 * g]);
            float p0 = exp2f(fmaf(s4[tt][0], 0.18033688011112042f, mv.x));
            float p1 = exp2f(fmaf(s4[tt][1], 0.18033688011112042f, mv.y));
            float p2 = exp2f(fmaf(s4[tt][2], 0.18033688011112042f, mv.z));
            float p3 = exp2f(fmaf(s4[tt][3], 0.18033688011112042f, mv.w));
            l_part += (p0 + p1) + (p2 + p3);
            s16x4 pk;
            pk[0] = (short)f2bf(p0); pk[1] = (short)f2bf(p1);
            pk[2] = (short)f2bf(p2); pk[3] = (short)f2bf(p3);
            *reinterpret_cast<s16x4*>(
                &Pl[wv][(ln * 64 + 16 * tt + 4 * g) ^ swz]) = pk;
        }

        // O += P @ V
        s16x8 pa[2];
        #pragma unroll
        for (int ks = 0; ks < 2; ++ks)
            pa[ks] = *reinterpret_cast<const s16x8*>(
                &Pl[wv][(ln * 64 + ks * 32 + g * 8) ^ swz]);
        #pragma unroll
        for (int tt = 0; tt < 4; ++tt) {
            int row = ln + 16 * tt;
            #pragma unroll
            for (int ks = 0; ks < 2; ++ks) {
                s16x8 vb = *reinterpret_cast<const s16x8*>(
                    &Vs[buf][(row * 64 + ks * 32 + g * 8) ^ swz]);
                Ot[tt] = __builtin_amdgcn_mfma_f32_16x16x32_bf16(pa[ks], vb, Ot[tt], 0, 0, 0);
            }
        }
        __syncthreads();
        buf ^= 1;
    }

    l_part += __shfl_xor(l_part, 16);
    l_part += __shfl_xor(l_part, 32);
    size_t obase = (size_t)(chunk * 16 + bh) * 2048 + qt * 64 + wv * 16;
    if (lane < 16) lp[obase + ln] = l_part;
    #pragma unroll
    for (int r = 0; r < 4; ++r)
        #pragma unroll
        for (int tt = 0; tt < 4; ++tt)
            OP[(obase + 4 * g + r) * 64 + ln + 16 * tt] = Ot[tt][r];
}

// ---------------- combine: out = (O0+O1)/(l0+l1) ---------------------------
__global__ __launch_bounds__(256) void combine(
    const float* __restrict__ OP, const float* __restrict__ lp,
    float* __restrict__ out)
{
    int id = blockIdx.x * 256 + threadIdx.x;   // 0..524287
    int w4 = id & 15;
    int h  = (id >> 4) & 7;
    int q  = (id >> 7) & 2047;
    int b  = id >> 18;
    int bh = b * 8 + h;
    size_t i0 = (size_t)bh * 2048 + q;
    const size_t C1O = (size_t)16 * 2048 * 64;
    const size_t C1L = (size_t)16 * 2048;
    float4 o0 = *reinterpret_cast<const float4*>(&OP[i0 * 64 + w4 * 4]);
    float4 o1 = *reinterpret_cast<const float4*>(&OP[C1O + i0 * 64 + w4 * 4]);
    float inv = 1.f / (lp[i0] + lp[C1L + i0]);
    float4 o;
    o.x = (o0.x + o1.x) * inv;
    o.y = (o0.y + o1.y) * inv;
    o.z = (o0.z + o1.z) * inv;
    o.w = (o0.w + o1.w) * inv;
    *reinterpret_cast<float4*>(
        &out[((size_t)b * 2048 + q) * 512 + h * 64 + w4 * 4]) = o;
}

extern "C" void kernel_launch(void* const* d_in, const int* in_sizes, int n_in,
                              void* d_out, int out_size, void* d_ws, size_t ws_size,
                              hipStream_t stream)
{
    const float* q    = (const float*)d_in[0];
    const float* k    = (const float*)d_in[1];
    const int*   mask = (const int*)  d_in[2];
    const float* Wq   = (const float*)d_in[3];
    const float* bq   = (const float*)d_in[4];
    const float* Wk   = (const float*)d_in[5];
    const float* bk   = (const float*)d_in[6];
    const float* Wv   = (const float*)d_in[7];
    const float* bv   = (const float*)d_in[8];
    float* out = (float*)d_out;

    unsigned short* p = (unsigned short*)d_ws;
    unsigned short* qh  = p; p += (size_t)2 * 8 * 2048 * 64;   // 4MB
    unsigned short* kh  = p; p += (size_t)2 * 8 * 4096 * 64;   // 8MB
    unsigned short* vt  = p; p += (size_t)2 * 8 * 4096 * 64;   // 8MB
    // region below is dual-use: proj inputs, then attention partials
    unsigned short* qbf = p;
    unsigned short* kbf = qbf + (size_t)2 * 2048 * 512;
    unsigned short* wtq = kbf + (size_t)2 * 4096 * 512;
    unsigned short* wtk = wtq + 512 * 512;
    unsigned short* wtv = wtk + 512 * 512;
    float* OP = (float*)p;                                      // 16.8MB
    float* lp = OP + (size_t)2 * 16 * 2048 * 64;                // 256KB

    dim3 blk(256);
    prep<<<dim3(3264), blk, 0, stream>>>(q, k, Wq, Wk, Wv, qbf, kbf, wtq, wtk, wtv);
    proj3<<<dim3(1280), blk, 0, stream>>>(qbf, kbf, wtq, wtk, wtv,
                                          bq, bk, bv, qh, kh, vt);
    attn3<<<dim3(64, 8, 2), blk, 0, stream>>>(qh, kh, vt, mask, OP, lp);
    combine<<<dim3(2048), blk, 0, stream>>>(OP, lp, out);
}

// Round 5
// 124.563 us; speedup vs baseline: 6.0793x; 1.0313x over previous
//
#include <hip/hip_runtime.h>
#include <hip/hip_bf16.h>

// R5: attn with 32KB LDS (4 blocks/CU co-resident), P written into Ks[buf]
// after a raw mid-tile s_barrier, precomputed float mask bias, cheap packed
// bf16 conversion, setprio around MFMA clusters. proj/prep/combine as R4
// (prep additionally builds mskf).

typedef short  s16x8 __attribute__((ext_vector_type(8)));
typedef short  s16x4 __attribute__((ext_vector_type(4)));
typedef float  f32x4 __attribute__((ext_vector_type(4)));

__device__ __forceinline__ unsigned short f2bf(float x) {
    return __builtin_bit_cast(unsigned short, __float2bfloat16(x));
}
// round-to-nearest(-away) and pack two f32 -> two bf16 in one u32
__device__ __forceinline__ unsigned int pk2(float a, float b) {
    unsigned int ua = __builtin_bit_cast(unsigned int, a) + 0x8000u;
    unsigned int ub = __builtin_bit_cast(unsigned int, b) + 0x8000u;
    return (ua >> 16) | (ub & 0xffff0000u);
}
__device__ __forceinline__ void gload16(const void* g, void* lds) {
    __builtin_amdgcn_global_load_lds(
        (const __attribute__((address_space(1))) unsigned int*)g,
        (__attribute__((address_space(3))) unsigned int*)lds, 16, 0, 0);
}

// ---------------- prep: cast q,k; transpose/cast W; build mskf -------------
__global__ __launch_bounds__(256) void prep(
    const float* __restrict__ q, const float* __restrict__ k,
    const float* __restrict__ Wq, const float* __restrict__ Wk,
    const float* __restrict__ Wv, const int* __restrict__ mask,
    unsigned short* __restrict__ qbf, unsigned short* __restrict__ kbf,
    unsigned short* __restrict__ wtq, unsigned short* __restrict__ wtk,
    unsigned short* __restrict__ wtv, float* __restrict__ mskf)
{
    __shared__ float T[64][65];
    const int bid = blockIdx.x;
    const int tid = threadIdx.x;
    if (bid < 3072) {
        const float* src = bid < 1024 ? q : k;
        unsigned short* dst = bid < 1024 ? qbf : kbf;
        int i = (bid < 1024 ? bid : bid - 1024) * 256 + tid;
        float4 a = reinterpret_cast<const float4*>(src)[2 * i];
        float4 b = reinterpret_cast<const float4*>(src)[2 * i + 1];
        s16x8 o;
        o[0] = (short)f2bf(a.x); o[1] = (short)f2bf(a.y);
        o[2] = (short)f2bf(a.z); o[3] = (short)f2bf(a.w);
        o[4] = (short)f2bf(b.x); o[5] = (short)f2bf(b.y);
        o[6] = (short)f2bf(b.z); o[7] = (short)f2bf(b.w);
        reinterpret_cast<s16x8*>(dst)[i] = o;
    } else if (bid < 3264) {
        int t = bid - 3072;
        int z = t >> 6;
        int tt = t & 63;
        const float* W = z == 0 ? Wq : z == 1 ? Wk : Wv;
        unsigned short* D = z == 0 ? wtq : z == 1 ? wtk : wtv;
        const int k0 = (tt >> 3) * 64, n0 = (tt & 7) * 64;
        const int r = tid >> 2, cq = tid & 3;
        #pragma unroll
        for (int p = 0; p < 4; ++p) {
            int c = (cq + 4 * p) * 4;
            float4 v = *reinterpret_cast<const float4*>(
                &W[(size_t)(k0 + r) * 512 + n0 + c]);
            T[c + 0][r] = v.x; T[c + 1][r] = v.y;
            T[c + 2][r] = v.z; T[c + 3][r] = v.w;
        }
        __syncthreads();
        #pragma unroll
        for (int p = 0; p < 4; ++p) {
            int kc = (cq + 4 * p) * 4;
            s16x4 o;
            o[0] = (short)f2bf(T[r][kc + 0]);
            o[1] = (short)f2bf(T[r][kc + 1]);
            o[2] = (short)f2bf(T[r][kc + 2]);
            o[3] = (short)f2bf(T[r][kc + 3]);
            *reinterpret_cast<s16x4*>(&D[(size_t)(n0 + r) * 512 + k0 + kc]) = o;
        }
    } else {
        int i = (bid - 3264) * 2048 + tid * 8;
        int4 m0 = *reinterpret_cast<const int4*>(&mask[i]);
        int4 m1 = *reinterpret_cast<const int4*>(&mask[i + 4]);
        const float C = -14426.950408889634f;
        float4 f0, f1;
        f0.x = C * (1.f - (float)m0.x); f0.y = C * (1.f - (float)m0.y);
        f0.z = C * (1.f - (float)m0.z); f0.w = C * (1.f - (float)m0.w);
        f1.x = C * (1.f - (float)m1.x); f1.y = C * (1.f - (float)m1.y);
        f1.z = C * (1.f - (float)m1.z); f1.w = C * (1.f - (float)m1.w);
        *reinterpret_cast<float4*>(&mskf[i])     = f0;
        *reinterpret_cast<float4*>(&mskf[i + 4]) = f1;
    }
}

// ---------------- fused 3-way projection GEMM, bf16 MFMA, 2-phase ----------
__global__ __launch_bounds__(256) void proj3(
    const unsigned short* __restrict__ qbf, const unsigned short* __restrict__ kbf,
    const unsigned short* __restrict__ wtq, const unsigned short* __restrict__ wtk,
    const unsigned short* __restrict__ wtv,
    const float* __restrict__ bq, const float* __restrict__ bk,
    const float* __restrict__ bv,
    unsigned short* __restrict__ qh, unsigned short* __restrict__ kh,
    unsigned short* __restrict__ vt)
{
    __shared__ unsigned short As[2][128 * 64];
    __shared__ unsigned short Bs[2][64 * 64];

    const int tid  = threadIdx.x;
    const int wv   = tid >> 6;
    const int lane = tid & 63;
    const int g    = lane >> 4;
    const int ln   = lane & 15;
    const int swz  = (ln & 7) << 3;

    const int id = blockIdx.x;
    const unsigned short *A, *Wt;
    const float* bias;
    unsigned short* dst;
    int S, trans, nb, mb;
    if (id < 256)      { A = qbf; Wt = wtq; bias = bq; dst = qh; S = 2048; trans = 0; nb = id & 7;         mb = id >> 3; }
    else if (id < 768) { A = kbf; Wt = wtk; bias = bk; dst = kh; S = 4096; trans = 0; nb = (id - 256) & 7; mb = (id - 256) >> 3; }
    else               { A = kbf; Wt = wtv; bias = bv; dst = vt; S = 4096; trans = 1; nb = (id - 768) & 7; mb = (id - 768) >> 3; }
    const int m0 = mb * 128, n0 = nb * 64;

    f32x4 acc[4][2];
    #pragma unroll
    for (int i = 0; i < 4; ++i)
        #pragma unroll
        for (int j = 0; j < 2; ++j) acc[i][j] = (f32x4)0.f;

    auto stage = [&](int bufn, int k0) {
        #pragma unroll
        for (int p = 0; p < 4; ++p) {
            int slot = p * 256 + tid;
            int row = slot >> 3, cb = slot & 7;
            int cbp = cb ^ (row & 7);
            gload16(&A[(size_t)(m0 + row) * 512 + k0 + cbp * 8], &As[bufn][slot * 8]);
        }
        #pragma unroll
        for (int p = 0; p < 2; ++p) {
            int slot = p * 256 + tid;
            int row = slot >> 3, cb = slot & 7;
            int cbp = cb ^ (row & 7);
            gload16(&Wt[(size_t)(n0 + row) * 512 + k0 + cbp * 8], &Bs[bufn][slot * 8]);
        }
    };

    stage(0, 0);
    __syncthreads();
    int buf = 0;
    for (int kk = 0; kk < 8; ++kk) {
        if (kk < 7) stage(buf ^ 1, (kk + 1) * 64);
        #pragma unroll
        for (int ks = 0; ks < 2; ++ks) {
            s16x8 fa[2], fb[4];
            #pragma unroll
            for (int mi = 0; mi < 2; ++mi)
                fa[mi] = *reinterpret_cast<const s16x8*>(
                    &As[buf][((wv * 32 + 16 * mi + ln) * 64 + ks * 32 + g * 8) ^ swz]);
            #pragma unroll
            for (int nj = 0; nj < 4; ++nj)
                fb[nj] = *reinterpret_cast<const s16x8*>(
                    &Bs[buf][((16 * nj + ln) * 64 + ks * 32 + g * 8) ^ swz]);
            if (!trans) {
                #pragma unroll
                for (int mi = 0; mi < 2; ++mi)
                    #pragma unroll
                    for (int nj = 0; nj < 4; ++nj)
                        acc[nj][mi] = __builtin_amdgcn_mfma_f32_16x16x32_bf16(
                            fa[mi], fb[nj], acc[nj][mi], 0, 0, 0);
            } else {
                #pragma unroll
                for (int nj = 0; nj < 4; ++nj)
                    #pragma unroll
                    for (int mi = 0; mi < 2; ++mi)
                        acc[nj][mi] = __builtin_amdgcn_mfma_f32_16x16x32_bf16(
                            fb[nj], fa[mi], acc[nj][mi], 0, 0, 0);
            }
        }
        __syncthreads();
        buf ^= 1;
    }

    const int h    = nb;
    const int bidx = m0 / S;
    const int s0   = m0 - bidx * S;

    if (!trans) {
        float bvv[4];
        #pragma unroll
        for (int nj = 0; nj < 4; ++nj) bvv[nj] = bias[n0 + 16 * nj + ln];
        unsigned short* base = dst + (size_t)(bidx * 8 + h) * S * 64;
        #pragma unroll
        for (int mi = 0; mi < 2; ++mi)
            #pragma unroll
            for (int r = 0; r < 4; ++r) {
                int s = s0 + wv * 32 + 16 * mi + 4 * g + r;
                #pragma unroll
                for (int nj = 0; nj < 4; ++nj)
                    base[(size_t)s * 64 + 16 * nj + ln] =
                        f2bf(acc[nj][mi][r] + bvv[nj]);
            }
    } else {
        unsigned short* base = dst + (size_t)(bidx * 8 + h) * 64 * (size_t)S;
        #pragma unroll
        for (int nj = 0; nj < 4; ++nj)
            #pragma unroll
            for (int r = 0; r < 4; ++r) {
                int w = 16 * nj + 4 * g + r;
                float bw = bias[n0 + w];
                #pragma unroll
                for (int mi = 0; mi < 2; ++mi)
                    base[(size_t)w * S + s0 + wv * 32 + 16 * mi + ln] =
                        f2bf(acc[nj][mi][r] + bw);
            }
    }
}

// ---------------- attention: split-KV x2, P-in-Ks, 32KB LDS ----------------
__global__ __launch_bounds__(256) void attn4(
    const unsigned short* __restrict__ qh,  // [B,8,2048,64] bf16
    const unsigned short* __restrict__ kh,  // [B,8,4096,64] bf16
    const unsigned short* __restrict__ vt,  // [B,8,64,4096] bf16 (V^T)
    const float* __restrict__ mskf,         // [B,4096] = -14427*(1-m)
    float* __restrict__ OP,                 // [chunk 2][bh 16][q 2048][w 64]
    float* __restrict__ lp)                 // [chunk 2][bh 16][q 2048]
{
    __shared__ unsigned short Ks[2][64 * 64];   // K tile; P overwrites after mid-barrier
    __shared__ unsigned short Vs[2][64 * 64];

    const int tid  = threadIdx.x;
    const int wv   = tid >> 6;
    const int lane = tid & 63;
    const int g    = lane >> 4;
    const int ln   = lane & 15;
    const int rswz = (ln & 7) << 3;
    const int prow = wv * 16 + ln;
    const int pswz = (prow & 7) << 3;

    const int qt    = blockIdx.x >> 1;
    const int chunk = blockIdx.x & 1;
    const int h  = blockIdx.y;
    const int b  = blockIdx.z;
    const int bh = b * 8 + h;
    const int kt0 = chunk * 2048;

    const unsigned short* Kg = kh + (size_t)bh * 4096 * 64;
    const unsigned short* Vg = vt + (size_t)bh * 64 * 4096;
    const unsigned short* Qg = qh + ((size_t)bh * 2048 + qt * 64 + wv * 16) * 64;
    const float* mbase = mskf + b * 4096;

    s16x8 bq[2];
    #pragma unroll
    for (int ks = 0; ks < 2; ++ks)
        bq[ks] = *reinterpret_cast<const s16x8*>(&Qg[ln * 64 + ks * 32 + g * 8]);

    f32x4 Ot[4];
    #pragma unroll
    for (int t = 0; t < 4; ++t) Ot[t] = (f32x4)0.f;
    float l_part = 0.f;

    auto stage = [&](int bufn, int kt) {
        #pragma unroll
        for (int p = 0; p < 2; ++p) {
            int slot = p * 256 + tid;
            int row = slot >> 3, cb = slot & 7;
            int cbp = cb ^ (row & 7);
            gload16(&Kg[(size_t)(kt + row) * 64 + cbp * 8], &Ks[bufn][slot * 8]);
            gload16(&Vg[(size_t)row * 4096 + kt + cbp * 8], &Vs[bufn][slot * 8]);
        }
    };

    stage(0, kt0);
    __syncthreads();
    int buf = 0;
    for (int t = 0; t < 32; ++t) {
        const int kt = kt0 + t * 64;
        // mask bias loads first (vmcnt retires in order; keeps prefetch in flight)
        float4 mv[4];
        #pragma unroll
        for (int tt = 0; tt < 4; ++tt)
            mv[tt] = *reinterpret_cast<const float4*>(&mbase[kt + 16 * tt + 4 * g]);
        if (t < 31) stage(buf ^ 1, kt + 64);

        // S^T = K Q^T  (rows = keys, cols = q)
        f32x4 s4[4];
        #pragma unroll
        for (int tt = 0; tt < 4; ++tt) s4[tt] = (f32x4)0.f;
        __builtin_amdgcn_s_setprio(1);
        #pragma unroll
        for (int tt = 0; tt < 4; ++tt) {
            int row = ln + 16 * tt;
            #pragma unroll
            for (int ks = 0; ks < 2; ++ks) {
                s16x8 ka = *reinterpret_cast<const s16x8*>(
                    &Ks[buf][(row * 64 + ks * 32 + g * 8) ^ rswz]);
                s4[tt] = __builtin_amdgcn_mfma_f32_16x16x32_bf16(ka, bq[ks], s4[tt], 0, 0, 0);
            }
        }
        __builtin_amdgcn_s_setprio(0);

        // all waves' K reads are consumed by the MFMAs above -> raw barrier,
        // no vmcnt drain (prefetch stays in flight), then P overwrites Ks[buf]
        asm volatile("s_barrier" ::: "memory");

        #pragma unroll
        for (int tt = 0; tt < 4; ++tt) {
            float p0 = exp2f(fmaf(s4[tt][0], 0.18033688011112042f, mv[tt].x));
            float p1 = exp2f(fmaf(s4[tt][1], 0.18033688011112042f, mv[tt].y));
            float p2 = exp2f(fmaf(s4[tt][2], 0.18033688011112042f, mv[tt].z));
            float p3 = exp2f(fmaf(s4[tt][3], 0.18033688011112042f, mv[tt].w));
            l_part += (p0 + p1) + (p2 + p3);
            uint2 w;
            w.x = pk2(p0, p1);
            w.y = pk2(p2, p3);
            *reinterpret_cast<uint2*>(
                &Ks[buf][(prow * 64 + 16 * tt + 4 * g) ^ pswz]) = w;
        }

        // O += P @ V
        s16x8 pa[2];
        #pragma unroll
        for (int ks = 0; ks < 2; ++ks)
            pa[ks] = *reinterpret_cast<const s16x8*>(
                &Ks[buf][(prow * 64 + ks * 32 + g * 8) ^ pswz]);
        __builtin_amdgcn_s_setprio(1);
        #pragma unroll
        for (int tt = 0; tt < 4; ++tt) {
            int row = ln + 16 * tt;
            #pragma unroll
            for (int ks = 0; ks < 2; ++ks) {
                s16x8 vb = *reinterpret_cast<const s16x8*>(
                    &Vs[buf][(row * 64 + ks * 32 + g * 8) ^ rswz]);
                Ot[tt] = __builtin_amdgcn_mfma_f32_16x16x32_bf16(pa[ks], vb, Ot[tt], 0, 0, 0);
            }
        }
        __builtin_amdgcn_s_setprio(0);
        __syncthreads();
        buf ^= 1;
    }

    l_part += __shfl_xor(l_part, 16);
    l_part += __shfl_xor(l_part, 32);
    size_t obase = (size_t)(chunk * 16 + bh) * 2048 + qt * 64 + wv * 16;
    if (lane < 16) lp[obase + ln] = l_part;
    #pragma unroll
    for (int r = 0; r < 4; ++r)
        #pragma unroll
        for (int tt = 0; tt < 4; ++tt)
            OP[(obase + 4 * g + r) * 64 + ln + 16 * tt] = Ot[tt][r];
}

// ---------------- combine: out = (O0+O1)/(l0+l1) ---------------------------
__global__ __launch_bounds__(256) void combine(
    const float* __restrict__ OP, const float* __restrict__ lp,
    float* __restrict__ out)
{
    int id = blockIdx.x * 256 + threadIdx.x;
    int w4 = id & 15;
    int h  = (id >> 4) & 7;
    int q  = (id >> 7) & 2047;
    int b  = id >> 18;
    int bh = b * 8 + h;
    size_t i0 = (size_t)bh * 2048 + q;
    const size_t C1O = (size_t)16 * 2048 * 64;
    const size_t C1L = (size_t)16 * 2048;
    float4 o0 = *reinterpret_cast<const float4*>(&OP[i0 * 64 + w4 * 4]);
    float4 o1 = *reinterpret_cast<const float4*>(&OP[C1O + i0 * 64 + w4 * 4]);
    float inv = 1.f / (lp[i0] + lp[C1L + i0]);
    float4 o;
    o.x = (o0.x + o1.x) * inv;
    o.y = (o0.y + o1.y) * inv;
    o.z = (o0.z + o1.z) * inv;
    o.w = (o0.w + o1.w) * inv;
    *reinterpret_cast<float4*>(
        &out[((size_t)b * 2048 + q) * 512 + h * 64 + w4 * 4]) = o;
}

extern "C" void kernel_launch(void* const* d_in, const int* in_sizes, int n_in,
                              void* d_out, int out_size, void* d_ws, size_t ws_size,
                              hipStream_t stream)
{
    const float* q    = (const float*)d_in[0];
    const float* k    = (const float*)d_in[1];
    const int*   mask = (const int*)  d_in[2];
    const float* Wq   = (const float*)d_in[3];
    const float* bq   = (const float*)d_in[4];
    const float* Wk   = (const float*)d_in[5];
    const float* bk   = (const float*)d_in[6];
    const float* Wv   = (const float*)d_in[7];
    const float* bv   = (const float*)d_in[8];
    float* out = (float*)d_out;

    unsigned short* p = (unsigned short*)d_ws;
    unsigned short* qh  = p; p += (size_t)2 * 8 * 2048 * 64;   // 4MB
    unsigned short* kh  = p; p += (size_t)2 * 8 * 4096 * 64;   // 8MB
    unsigned short* vt  = p; p += (size_t)2 * 8 * 4096 * 64;   // 8MB
    // dual-use region: proj inputs, then attention partials
    unsigned short* alias = p;
    unsigned short* qbf = alias;
    unsigned short* kbf = qbf + (size_t)2 * 2048 * 512;
    unsigned short* wtq = kbf + (size_t)2 * 4096 * 512;
    unsigned short* wtk = wtq + 512 * 512;
    unsigned short* wtv = wtk + 512 * 512;
    float* OP = (float*)alias;                                  // 16MB
    float* lp = OP + (size_t)2 * 16 * 2048 * 64;                // 256KB
    float* mskf = lp + (size_t)2 * 16 * 2048;                   // 32KB (beyond both uses)

    dim3 blk(256);
    prep<<<dim3(3268), blk, 0, stream>>>(q, k, Wq, Wk, Wv, mask,
                                         qbf, kbf, wtq, wtk, wtv, mskf);
    proj3<<<dim3(1280), blk, 0, stream>>>(qbf, kbf, wtq, wtk, wtv,
                                          bq, bk, bv, qh, kh, vt);
    attn4<<<dim3(64, 8, 2), blk, 0, stream>>>(qh, kh, vt, mskf, OP, lp);
    combine<<<dim3(2048), blk, 0, stream>>>(OP, lp, out);
}

// Round 6
// 113.682 us; speedup vs baseline: 6.6612x; 1.0957x over previous
//
#include <hip/hip_runtime.h>
#include <hip/hip_bf16.h>

// R6: LDS-free attention main loop. 32x32x16 bf16 MFMA; per-wave-exclusive
// K/V key-quarters loaded global->register; Q in registers; P kept in
// registers via v_cvt_pk_bf16_f32 + v_permlane32_swap_b32; per-wave partial
// O reduced across waves via a small 4-pass LDS reduction at the end.
// QBLK=128, KVBLK=128, 8 waves/block, grid=256 (1 block/CU, XCD-clustered).

typedef short  s16x8 __attribute__((ext_vector_type(8)));
typedef short  s16x4 __attribute__((ext_vector_type(4)));
typedef float  f32x4 __attribute__((ext_vector_type(4)));
typedef float  f32x16 __attribute__((ext_vector_type(16)));
typedef unsigned int u32;
typedef unsigned int u32x4 __attribute__((ext_vector_type(4)));

__device__ __forceinline__ unsigned short f2bf(float x) {
    return __builtin_bit_cast(unsigned short, __float2bfloat16(x));
}
__device__ __forceinline__ void gload16(const void* g, void* lds) {
    __builtin_amdgcn_global_load_lds(
        (const __attribute__((address_space(1))) unsigned int*)g,
        (__attribute__((address_space(3))) unsigned int*)lds, 16, 0, 0);
}
__device__ __forceinline__ u32 cvtpk(float lo, float hi) {
    u32 r;
    asm("v_cvt_pk_bf16_f32 %0, %1, %2" : "=v"(r) : "v"(lo), "v"(hi));
    return r;
}

// ---------------- prep: cast q,k; transpose/cast W; build mskf -------------
__global__ __launch_bounds__(256) void prep(
    const float* __restrict__ q, const float* __restrict__ k,
    const float* __restrict__ Wq, const float* __restrict__ Wk,
    const float* __restrict__ Wv, const int* __restrict__ mask,
    unsigned short* __restrict__ qbf, unsigned short* __restrict__ kbf,
    unsigned short* __restrict__ wtq, unsigned short* __restrict__ wtk,
    unsigned short* __restrict__ wtv, float* __restrict__ mskf)
{
    __shared__ float T[64][65];
    const int bid = blockIdx.x;
    const int tid = threadIdx.x;
    if (bid < 3072) {
        const float* src = bid < 1024 ? q : k;
        unsigned short* dst = bid < 1024 ? qbf : kbf;
        int i = (bid < 1024 ? bid : bid - 1024) * 256 + tid;
        float4 a = reinterpret_cast<const float4*>(src)[2 * i];
        float4 b = reinterpret_cast<const float4*>(src)[2 * i + 1];
        s16x8 o;
        o[0] = (short)f2bf(a.x); o[1] = (short)f2bf(a.y);
        o[2] = (short)f2bf(a.z); o[3] = (short)f2bf(a.w);
        o[4] = (short)f2bf(b.x); o[5] = (short)f2bf(b.y);
        o[6] = (short)f2bf(b.z); o[7] = (short)f2bf(b.w);
        reinterpret_cast<s16x8*>(dst)[i] = o;
    } else if (bid < 3264) {
        int t = bid - 3072;
        int z = t >> 6;
        int tt = t & 63;
        const float* W = z == 0 ? Wq : z == 1 ? Wk : Wv;
        unsigned short* D = z == 0 ? wtq : z == 1 ? wtk : wtv;
        const int k0 = (tt >> 3) * 64, n0 = (tt & 7) * 64;
        const int r = tid >> 2, cq = tid & 3;
        #pragma unroll
        for (int p = 0; p < 4; ++p) {
            int c = (cq + 4 * p) * 4;
            float4 v = *reinterpret_cast<const float4*>(
                &W[(size_t)(k0 + r) * 512 + n0 + c]);
            T[c + 0][r] = v.x; T[c + 1][r] = v.y;
            T[c + 2][r] = v.z; T[c + 3][r] = v.w;
        }
        __syncthreads();
        #pragma unroll
        for (int p = 0; p < 4; ++p) {
            int kc = (cq + 4 * p) * 4;
            s16x4 o;
            o[0] = (short)f2bf(T[r][kc + 0]);
            o[1] = (short)f2bf(T[r][kc + 1]);
            o[2] = (short)f2bf(T[r][kc + 2]);
            o[3] = (short)f2bf(T[r][kc + 3]);
            *reinterpret_cast<s16x4*>(&D[(size_t)(n0 + r) * 512 + k0 + kc]) = o;
        }
    } else {
        int i = (bid - 3264) * 2048 + tid * 8;
        int4 m0 = *reinterpret_cast<const int4*>(&mask[i]);
        int4 m1 = *reinterpret_cast<const int4*>(&mask[i + 4]);
        const float C = -14426.950408889634f;
        float4 f0, f1;
        f0.x = C * (1.f - (float)m0.x); f0.y = C * (1.f - (float)m0.y);
        f0.z = C * (1.f - (float)m0.z); f0.w = C * (1.f - (float)m0.w);
        f1.x = C * (1.f - (float)m1.x); f1.y = C * (1.f - (float)m1.y);
        f1.z = C * (1.f - (float)m1.z); f1.w = C * (1.f - (float)m1.w);
        *reinterpret_cast<float4*>(&mskf[i])     = f0;
        *reinterpret_cast<float4*>(&mskf[i + 4]) = f1;
    }
}

// ---------------- fused 3-way projection GEMM, bf16 MFMA, 2-phase ----------
__global__ __launch_bounds__(256) void proj3(
    const unsigned short* __restrict__ qbf, const unsigned short* __restrict__ kbf,
    const unsigned short* __restrict__ wtq, const unsigned short* __restrict__ wtk,
    const unsigned short* __restrict__ wtv,
    const float* __restrict__ bq, const float* __restrict__ bk,
    const float* __restrict__ bv,
    unsigned short* __restrict__ qh, unsigned short* __restrict__ kh,
    unsigned short* __restrict__ vt)
{
    __shared__ unsigned short As[2][128 * 64];
    __shared__ unsigned short Bs[2][64 * 64];

    const int tid  = threadIdx.x;
    const int wv   = tid >> 6;
    const int lane = tid & 63;
    const int g    = lane >> 4;
    const int ln   = lane & 15;
    const int swz  = (ln & 7) << 3;

    const int id = blockIdx.x;
    const unsigned short *A, *Wt;
    const float* bias;
    unsigned short* dst;
    int S, trans, nb, mb;
    if (id < 256)      { A = qbf; Wt = wtq; bias = bq; dst = qh; S = 2048; trans = 0; nb = id & 7;         mb = id >> 3; }
    else if (id < 768) { A = kbf; Wt = wtk; bias = bk; dst = kh; S = 4096; trans = 0; nb = (id - 256) & 7; mb = (id - 256) >> 3; }
    else               { A = kbf; Wt = wtv; bias = bv; dst = vt; S = 4096; trans = 1; nb = (id - 768) & 7; mb = (id - 768) >> 3; }
    const int m0 = mb * 128, n0 = nb * 64;

    f32x4 acc[4][2];
    #pragma unroll
    for (int i = 0; i < 4; ++i)
        #pragma unroll
        for (int j = 0; j < 2; ++j) acc[i][j] = (f32x4)0.f;

    auto stage = [&](int bufn, int k0) {
        #pragma unroll
        for (int p = 0; p < 4; ++p) {
            int slot = p * 256 + tid;
            int row = slot >> 3, cb = slot & 7;
            int cbp = cb ^ (row & 7);
            gload16(&A[(size_t)(m0 + row) * 512 + k0 + cbp * 8], &As[bufn][slot * 8]);
        }
        #pragma unroll
        for (int p = 0; p < 2; ++p) {
            int slot = p * 256 + tid;
            int row = slot >> 3, cb = slot & 7;
            int cbp = cb ^ (row & 7);
            gload16(&Wt[(size_t)(n0 + row) * 512 + k0 + cbp * 8], &Bs[bufn][slot * 8]);
        }
    };

    stage(0, 0);
    __syncthreads();
    int buf = 0;
    for (int kk = 0; kk < 8; ++kk) {
        if (kk < 7) stage(buf ^ 1, (kk + 1) * 64);
        #pragma unroll
        for (int ks = 0; ks < 2; ++ks) {
            s16x8 fa[2], fb[4];
            #pragma unroll
            for (int mi = 0; mi < 2; ++mi)
                fa[mi] = *reinterpret_cast<const s16x8*>(
                    &As[buf][((wv * 32 + 16 * mi + ln) * 64 + ks * 32 + g * 8) ^ swz]);
            #pragma unroll
            for (int nj = 0; nj < 4; ++nj)
                fb[nj] = *reinterpret_cast<const s16x8*>(
                    &Bs[buf][((16 * nj + ln) * 64 + ks * 32 + g * 8) ^ swz]);
            if (!trans) {
                #pragma unroll
                for (int mi = 0; mi < 2; ++mi)
                    #pragma unroll
                    for (int nj = 0; nj < 4; ++nj)
                        acc[nj][mi] = __builtin_amdgcn_mfma_f32_16x16x32_bf16(
                            fa[mi], fb[nj], acc[nj][mi], 0, 0, 0);
            } else {
                #pragma unroll
                for (int nj = 0; nj < 4; ++nj)
                    #pragma unroll
                    for (int mi = 0; mi < 2; ++mi)
                        acc[nj][mi] = __builtin_amdgcn_mfma_f32_16x16x32_bf16(
                            fb[nj], fa[mi], acc[nj][mi], 0, 0, 0);
            }
        }
        __syncthreads();
        buf ^= 1;
    }

    const int h    = nb;
    const int bidx = m0 / S;
    const int s0   = m0 - bidx * S;

    if (!trans) {
        float bvv[4];
        #pragma unroll
        for (int nj = 0; nj < 4; ++nj) bvv[nj] = bias[n0 + 16 * nj + ln];
        unsigned short* base = dst + (size_t)(bidx * 8 + h) * S * 64;
        #pragma unroll
        for (int mi = 0; mi < 2; ++mi)
            #pragma unroll
            for (int r = 0; r < 4; ++r) {
                int s = s0 + wv * 32 + 16 * mi + 4 * g + r;
                #pragma unroll
                for (int nj = 0; nj < 4; ++nj)
                    base[(size_t)s * 64 + 16 * nj + ln] =
                        f2bf(acc[nj][mi][r] + bvv[nj]);
            }
    } else {
        unsigned short* base = dst + (size_t)(bidx * 8 + h) * 64 * (size_t)S;
        #pragma unroll
        for (int nj = 0; nj < 4; ++nj)
            #pragma unroll
            for (int r = 0; r < 4; ++r) {
                int w = 16 * nj + 4 * g + r;
                float bw = bias[n0 + w];
                #pragma unroll
                for (int mi = 0; mi < 2; ++mi)
                    base[(size_t)w * S + s0 + wv * 32 + 16 * mi + ln] =
                        f2bf(acc[nj][mi][r] + bw);
            }
    }
}

// ---------------- attention: LDS-free loop, 32x32 MFMA, P in registers -----
__global__ __launch_bounds__(512, 2) void attn5(
    const unsigned short* __restrict__ qh,  // [B,8,2048,64] bf16
    const unsigned short* __restrict__ kh,  // [B,8,4096,64] bf16
    const unsigned short* __restrict__ vt,  // [B,8,64,4096] bf16 (V^T)
    const float* __restrict__ mskf,         // [B,4096] = -14427*(1-m)
    float* __restrict__ out)                // [B,2048,512]
{
    __shared__ float Ored[2][4][32][36];    // [qgroup][kq][q32][w32+pad]
    __shared__ float lw[2][2][4][32];       // [qgroup][qt2][kq][q31]

    const int tid  = threadIdx.x;
    const int wid  = tid >> 6;
    const int kq   = wid & 3;       // key-quarter owner
    const int qg   = wid >> 2;      // q-half (64 rows)
    const int lane = tid & 63;
    const int l31  = lane & 31;
    const int h32  = lane >> 5;

    // XCD-clustered mapping: blocks sharing (b,h) land on one XCD's L2
    const int id  = blockIdx.x;
    const int xcd = id & 7;
    const int j   = id >> 3;
    const int bh  = xcd * 2 + (j >> 4);     // = b*8+h
    const int qt  = j & 15;
    const int b   = bh >> 3;
    const int hh  = bh & 7;

    const unsigned short* Kp = kh + (size_t)bh * 4096 * 64
                               + (size_t)(kq * 32 + l31) * 64 + h32 * 8;
    const unsigned short* Vp0 = vt + (size_t)bh * 64 * 4096
                               + (size_t)(l31) * 4096 + kq * 32 + h32 * 8;
    const float* mp = mskf + b * 4096 + kq * 32 + h32 * 4;

    // Q fragments (B operand): col = l31, k = ks*16 + 8*h32 + j
    s16x8 Qf[2][4];
    {
        const unsigned short* Qb = qh + ((size_t)bh * 2048 + qt * 128 + qg * 64) * 64;
        #pragma unroll
        for (int qt2 = 0; qt2 < 2; ++qt2)
            #pragma unroll
            for (int ks = 0; ks < 4; ++ks)
                Qf[qt2][ks] = *reinterpret_cast<const s16x8*>(
                    &Qb[(size_t)(qt2 * 32 + l31) * 64 + ks * 16 + h32 * 8]);
    }

    f32x16 O[2][2];
    #pragma unroll
    for (int i = 0; i < 2; ++i)
        #pragma unroll
        for (int jj = 0; jj < 2; ++jj) O[i][jj] = (f32x16)0.f;
    float l_acc0 = 0.f, l_acc1 = 0.f;

    s16x8 kf[4], vf[4];
    float4 mk[4];

    auto loadK = [&](int t) {
        #pragma unroll
        for (int ks = 0; ks < 4; ++ks)
            kf[ks] = *reinterpret_cast<const s16x8*>(Kp + (size_t)t * 8192 + ks * 16);
    };
    auto loadV = [&](int t) {
        #pragma unroll
        for (int wt = 0; wt < 2; ++wt)
            #pragma unroll
            for (int t2 = 0; t2 < 2; ++t2)
                vf[wt * 2 + t2] = *reinterpret_cast<const s16x8*>(
                    Vp0 + (size_t)wt * 32 * 4096 + t * 128 + t2 * 16);
    };
    auto loadM = [&](int t) {
        #pragma unroll
        for (int m = 0; m < 4; ++m)
            mk[m] = *reinterpret_cast<const float4*>(mp + t * 128 + m * 8);
    };

    loadM(0); loadK(0); loadV(0);

    for (int t = 0; t < 32; ++t) {
        // ---- QK^T: S^T[32 keys][64 q] = K x Q --------------------------
        f32x16 S[2];
        S[0] = (f32x16)0.f; S[1] = (f32x16)0.f;
        __builtin_amdgcn_s_setprio(1);
        #pragma unroll
        for (int ks = 0; ks < 4; ++ks) {
            S[0] = __builtin_amdgcn_mfma_f32_32x32x16_bf16(kf[ks], Qf[0][ks], S[0], 0, 0, 0);
            S[1] = __builtin_amdgcn_mfma_f32_32x32x16_bf16(kf[ks], Qf[1][ks], S[1], 0, 0, 0);
        }
        __builtin_amdgcn_s_setprio(0);
        if (t < 31) loadK(t + 1);

        // ---- softmax (no-max) + pack P to bf16 A-frags -----------------
        // S reg r <-> key kr = (r&3) + 8*(r>>2) + 4*h32 ; bias = mk[r>>2][r&3]
        s16x8 pa[2][2];
        #pragma unroll
        for (int qt2 = 0; qt2 < 2; ++qt2) {
            float pp[16];
            #pragma unroll
            for (int r = 0; r < 16; ++r) {
                float mb_ = (r & 3) == 0 ? mk[r >> 2].x :
                            (r & 3) == 1 ? mk[r >> 2].y :
                            (r & 3) == 2 ? mk[r >> 2].z : mk[r >> 2].w;
                pp[r] = exp2f(fmaf(S[qt2][r], 0.18033688011112042f, mb_));
            }
            float ls = ((pp[0] + pp[1]) + (pp[2] + pp[3]))
                     + ((pp[4] + pp[5]) + (pp[6] + pp[7]))
                     + ((pp[8] + pp[9]) + (pp[10] + pp[11]))
                     + ((pp[12] + pp[13]) + (pp[14] + pp[15]));
            if (qt2 == 0) l_acc0 += ls; else l_acc1 += ls;
            // W[2c+d] = pack(p[4c+2d], p[4c+2d+1]) ; c=0..3, d=0..1
            u32 W[8];
            #pragma unroll
            for (int c = 0; c < 4; ++c) {
                W[2 * c + 0] = cvtpk(pp[4 * c + 0], pp[4 * c + 1]);
                W[2 * c + 1] = cvtpk(pp[4 * c + 2], pp[4 * c + 3]);
            }
            // swap W[m] <-> W[m+2]: after this, A-frag(t2) = W[4*t2 .. 4*t2+3]
            asm("v_permlane32_swap_b32 %0, %1" : "+v"(W[0]), "+v"(W[2]));
            asm("v_permlane32_swap_b32 %0, %1" : "+v"(W[1]), "+v"(W[3]));
            asm("v_permlane32_swap_b32 %0, %1" : "+v"(W[4]), "+v"(W[6]));
            asm("v_permlane32_swap_b32 %0, %1" : "+v"(W[5]), "+v"(W[7]));
            u32x4 lo, hi;
            lo[0] = W[0]; lo[1] = W[1]; lo[2] = W[2]; lo[3] = W[3];
            hi[0] = W[4]; hi[1] = W[5]; hi[2] = W[6]; hi[3] = W[7];
            pa[qt2][0] = __builtin_bit_cast(s16x8, lo);
            pa[qt2][1] = __builtin_bit_cast(s16x8, hi);
        }

        // ---- PV: O[q][w] += P x V --------------------------------------
        __builtin_amdgcn_s_setprio(1);
        #pragma unroll
        for (int qt2 = 0; qt2 < 2; ++qt2)
            #pragma unroll
            for (int wt = 0; wt < 2; ++wt)
                #pragma unroll
                for (int t2 = 0; t2 < 2; ++t2)
                    O[qt2][wt] = __builtin_amdgcn_mfma_f32_32x32x16_bf16(
                        pa[qt2][t2], vf[wt * 2 + t2], O[qt2][wt], 0, 0, 0);
        __builtin_amdgcn_s_setprio(0);
        if (t < 31) { loadV(t + 1); loadM(t + 1); }
    }

    // ---- l reduction: lane pair (h32) then cross-wave via LDS -----------
    float ls0 = l_acc0 + __shfl_xor(l_acc0, 32);
    float ls1 = l_acc1 + __shfl_xor(l_acc1, 32);
    if (lane < 32) {
        lw[qg][0][kq][l31] = ls0;
        lw[qg][1][kq][l31] = ls1;
    }

    // ---- O reduction across the 4 key-quarter waves, 4 passes -----------
    const int grp = tid >> 8;          // q-group of this thread (0/1)
    const int tt  = tid & 255;
    const int qr  = tt >> 3;           // 0..31
    const int w8  = (tt & 7) * 4;      // 0..28
    #pragma unroll
    for (int qt2 = 0; qt2 < 2; ++qt2)
        #pragma unroll
        for (int wt = 0; wt < 2; ++wt) {
            __syncthreads();
            f32x16 oo = O[qt2][wt];
            #pragma unroll
            for (int r = 0; r < 16; ++r)
                Ored[qg][kq][(r & 3) + 8 * (r >> 2) + 4 * h32][l31] = oo[r];
            __syncthreads();
            float4 s = *reinterpret_cast<const float4*>(&Ored[grp][0][qr][w8]);
            float4 s1 = *reinterpret_cast<const float4*>(&Ored[grp][1][qr][w8]);
            float4 s2 = *reinterpret_cast<const float4*>(&Ored[grp][2][qr][w8]);
            float4 s3 = *reinterpret_cast<const float4*>(&Ored[grp][3][qr][w8]);
            s.x += s1.x + s2.x + s3.x;
            s.y += s1.y + s2.y + s3.y;
            s.z += s1.z + s2.z + s3.z;
            s.w += s1.w + s2.w + s3.w;
            float l = lw[grp][qt2][0][qr] + lw[grp][qt2][1][qr]
                    + lw[grp][qt2][2][qr] + lw[grp][qt2][3][qr];
            float inv = 1.f / l;
            int qglob = qt * 128 + grp * 64 + qt2 * 32 + qr;
            float4 o;
            o.x = s.x * inv; o.y = s.y * inv; o.z = s.z * inv; o.w = s.w * inv;
            *reinterpret_cast<float4*>(
                &out[((size_t)b * 2048 + qglob) * 512 + hh * 64 + wt * 32 + w8]) = o;
        }
}

extern "C" void kernel_launch(void* const* d_in, const int* in_sizes, int n_in,
                              void* d_out, int out_size, void* d_ws, size_t ws_size,
                              hipStream_t stream)
{
    const float* q    = (const float*)d_in[0];
    const float* k    = (const float*)d_in[1];
    const int*   mask = (const int*)  d_in[2];
    const float* Wq   = (const float*)d_in[3];
    const float* bq   = (const float*)d_in[4];
    const float* Wk   = (const float*)d_in[5];
    const float* bk   = (const float*)d_in[6];
    const float* Wv   = (const float*)d_in[7];
    const float* bv   = (const float*)d_in[8];
    float* out = (float*)d_out;

    unsigned short* p = (unsigned short*)d_ws;
    unsigned short* qh  = p; p += (size_t)2 * 8 * 2048 * 64;   // 4MB
    unsigned short* kh  = p; p += (size_t)2 * 8 * 4096 * 64;   // 8MB
    unsigned short* vt  = p; p += (size_t)2 * 8 * 4096 * 64;   // 8MB
    unsigned short* qbf = p; p += (size_t)2 * 2048 * 512;      // 4MB
    unsigned short* kbf = p; p += (size_t)2 * 4096 * 512;      // 8MB
    unsigned short* wtq = p; p += 512 * 512;
    unsigned short* wtk = p; p += 512 * 512;
    unsigned short* wtv = p; p += 512 * 512;
    float* mskf = (float*)p;                                    // 32KB

    dim3 blk(256);
    prep<<<dim3(3268), blk, 0, stream>>>(q, k, Wq, Wk, Wv, mask,
                                         qbf, kbf, wtq, wtk, wtv, mskf);
    proj3<<<dim3(1280), blk, 0, stream>>>(qbf, kbf, wtq, wtk, wtv,
                                          bq, bk, bv, qh, kh, vt);
    attn5<<<dim3(256), dim3(512), 0, stream>>>(qh, kh, vt, mskf, out);
}